// Round 3
// baseline (654.448 us; speedup 1.0000x reference)
//
#include <hip/hip_runtime.h>
#include <math.h>

#define B_ 8192
#define IN_ 8000
#define C_ 16
#define S_ 500
#define O_ 64
#define F_ 1024
#define E_ 8
#define D_ 512
#define T_ 2
#define OUTW 34
#define EPS_ 1e-5f

typedef __attribute__((ext_vector_type(8))) short bf16x8;
typedef __attribute__((ext_vector_type(4))) float f32x4;

__device__ __forceinline__ float swishf(float x) {
    return x / (1.0f + __expf(-x));
}

// round-to-nearest-even f32 -> bf16 bits
__device__ __forceinline__ unsigned short f2bf(float f) {
    union { float f; unsigned u; } c;
    c.f = f;
    unsigned r = c.u + 0x7fffu + ((c.u >> 16) & 1u);
    return (unsigned short)(r >> 16);
}
__device__ __forceinline__ float bf2f(unsigned short b) {
    union { unsigned u; float f; } c;
    c.u = ((unsigned)b) << 16;
    return c.f;
}

// async global->LDS, 16B per lane; LDS dest is wave-uniform base + lane*16
__device__ __forceinline__ void gld16(const void* g, void* l) {
    __builtin_amdgcn_global_load_lds(
        (const __attribute__((address_space(1))) void*)g,
        (__attribute__((address_space(3))) void*)l, 16, 0, 0);
}

// -------------------- SplitLinear via bf16 MFMA + fused bias + BN0 partial stats --------------------
// T14 async-stage split: iter t writes LDS from regs, barriers, ISSUES t+1's global loads,
// then MFMAs — vmcnt wait lands after MFMA+barrier instead of serializing every step.
__global__ __launch_bounds__(256) void k_split(const float* __restrict__ x,
                                               const float* __restrict__ w0,
                                               const float* __restrict__ b0,
                                               unsigned short* __restrict__ h0raw,
                                               float* __restrict__ psum,
                                               float* __restrict__ psq) {
    __shared__ __align__(16) unsigned short As[128 * 72];  // [row][72] padded
    __shared__ __align__(16) unsigned short Bs[64 * 72];
    int tid = threadIdx.x;
    int c = blockIdx.y;
    int brow0 = blockIdx.x * 128;
    const float* xp = x + (size_t)brow0 * IN_ + c * S_;
    const float* wp = w0 + (size_t)c * O_ * S_;

    int w = tid >> 6, lane = tid & 63;
    int l15 = lane & 15, quad = lane >> 4;
    int wm = w * 32;

    int srow = tid >> 4, sc4 = tid & 15;
    int gkbase = sc4 * 4;

    f32x4 acc[2][4] = {};
    float4 ra[8], rw[4];

#define LOAD_AB(k0) do {                                                                   \
    int gk = (k0) + gkbase;                                                                \
    bool ok = (gk + 3 < S_);                                                               \
    _Pragma("unroll")                                                                      \
    for (int i = 0; i < 8; i++) {                                                          \
        ra[i] = make_float4(0.f, 0.f, 0.f, 0.f);                                           \
        if (ok) ra[i] = *(const float4*)(xp + (size_t)(srow + i * 16) * IN_ + gk);         \
    }                                                                                      \
    _Pragma("unroll")                                                                      \
    for (int i = 0; i < 4; i++) {                                                          \
        rw[i] = make_float4(0.f, 0.f, 0.f, 0.f);                                           \
        if (ok) rw[i] = *(const float4*)(wp + (size_t)(srow + i * 16) * S_ + gk);          \
    }                                                                                      \
} while (0)

#define WRITE_AB() do {                                                                    \
    _Pragma("unroll")                                                                      \
    for (int i = 0; i < 8; i++) {                                                          \
        unsigned short u[4] = { f2bf(ra[i].x), f2bf(ra[i].y), f2bf(ra[i].z), f2bf(ra[i].w) };\
        *(ushort4*)&As[(srow + i * 16) * 72 + sc4 * 4] = *(ushort4*)u;                     \
    }                                                                                      \
    _Pragma("unroll")                                                                      \
    for (int i = 0; i < 4; i++) {                                                          \
        unsigned short u[4] = { f2bf(rw[i].x), f2bf(rw[i].y), f2bf(rw[i].z), f2bf(rw[i].w) };\
        *(ushort4*)&Bs[(srow + i * 16) * 72 + sc4 * 4] = *(ushort4*)u;                     \
    }                                                                                      \
} while (0)

    LOAD_AB(0);
#pragma unroll
    for (int it = 0; it < 8; it++) {
        WRITE_AB();
        __syncthreads();
        if (it < 7) LOAD_AB((it + 1) * 64);   // prefetch next step (overlaps MFMA below)
#pragma unroll
        for (int kk = 0; kk < 64; kk += 32) {
            bf16x8 af[2], wf[4];
#pragma unroll
            for (int i = 0; i < 2; i++)
                af[i] = *(const bf16x8*)&As[(wm + i * 16 + l15) * 72 + kk + quad * 8];
#pragma unroll
            for (int j = 0; j < 4; j++)
                wf[j] = *(const bf16x8*)&Bs[(j * 16 + l15) * 72 + kk + quad * 8];
#pragma unroll
            for (int i = 0; i < 2; i++)
#pragma unroll
                for (int j = 0; j < 4; j++)
                    acc[i][j] = __builtin_amdgcn_mfma_f32_16x16x32_bf16(af[i], wf[j], acc[i][j], 0, 0, 0);
        }
        __syncthreads();
    }
#undef LOAD_AB
#undef WRITE_AB

    // epilogue: bias, bf16 store, column partial stats
    int colbase = c * O_;
    float sj[4], qj[4];
#pragma unroll
    for (int j = 0; j < 4; j++) {
        int col = j * 16 + l15;
        float bb = b0[colbase + col];
        float s = 0.f, q = 0.f;
#pragma unroll
        for (int i = 0; i < 2; i++) {
#pragma unroll
            for (int reg = 0; reg < 4; reg++) {
                float v = acc[i][j][reg] + bb;
                int rl = wm + i * 16 + quad * 4 + reg;
                h0raw[(size_t)(brow0 + rl) * F_ + colbase + col] = f2bf(v);
                s += v; q += v * v;
            }
        }
        s += __shfl_down(s, 32, 64); s += __shfl_down(s, 16, 64);
        q += __shfl_down(q, 32, 64); q += __shfl_down(q, 16, 64);
        sj[j] = s; qj[j] = q;
    }
    __syncthreads();
    float* red = (float*)As;
    if (lane < 16) {
#pragma unroll
        for (int j = 0; j < 4; j++) {
            int col = j * 16 + l15;
            red[col * 4 + w] = sj[j];
            red[256 + col * 4 + w] = qj[j];
        }
    }
    __syncthreads();
    if (tid < 64) {
        float ss = red[tid * 4] + red[tid * 4 + 1] + red[tid * 4 + 2] + red[tid * 4 + 3];
        float qq = red[256 + tid * 4] + red[256 + tid * 4 + 1] + red[256 + tid * 4 + 2] + red[256 + tid * 4 + 3];
        size_t idx = (size_t)blockIdx.x * F_ + colbase + tid;
        psum[idx] = ss; psq[idx] = qq;
    }
}

// -------------------- Column stats finalize --------------------
__global__ __launch_bounds__(64) void k_stats_b(const float* __restrict__ psum,
                                                const float* __restrict__ psq,
                                                int N, int YS,
                                                const float* __restrict__ g,
                                                const float* __restrict__ beta,
                                                unsigned long long gslab,
                                                float* __restrict__ scale,
                                                float* __restrict__ shift,
                                                unsigned long long oslab) {
    int n = blockIdx.x * 64 + threadIdx.x;
    int z = blockIdx.z;
    float s = 0.f, q = 0.f;
    for (int y = 0; y < YS; y++) {
        size_t idx = ((size_t)(z * YS + y)) * N + n;
        s += psum[idx]; q += psq[idx];
    }
    float mean = s * (1.0f / B_);
    float var = q * (1.0f / B_) - mean * mean;
    float sc = g[z * gslab + n] * rsqrtf(var + EPS_);
    scale[z * oslab + n] = sc;
    shift[z * oslab + n] = beta[z * gslab + n] - mean * sc;
}

// -------------------- transpose-convert: in [Z][K][N] f32 -> out [Z][N][K] bf16 --------------------
__global__ __launch_bounds__(256) void k_wt(const float* __restrict__ in,
                                            unsigned short* __restrict__ out,
                                            int K, int N) {
    __shared__ float t[32][33];
    int k0 = blockIdx.x * 32, n0 = blockIdx.y * 32, z = blockIdx.z;
    const float* ip = in + (size_t)z * K * N;
    unsigned short* op = out + (size_t)z * N * K;
    int tn = threadIdx.x & 31, tk = threadIdx.x >> 5;
#pragma unroll
    for (int p = 0; p < 4; p++) {
        int k = tk + p * 8;
        t[k][tn] = ip[(size_t)(k0 + k) * N + n0 + tn];
    }
    __syncthreads();
    int tk2 = threadIdx.x & 31, tn2 = threadIdx.x >> 5;
#pragma unroll
    for (int p = 0; p < 4; p++) {
        int n = tn2 + p * 8;
        op[(size_t)(n0 + n) * K + k0 + tk2] = f2bf(t[tk2][n]);
    }
}

// -------------------- BN0 apply + swish (pure elementwise): h0raw -> h0bf --------------------
__global__ __launch_bounds__(256) void k_bnswish(const unsigned short* __restrict__ h0,
                                                 const float* __restrict__ scale,
                                                 const float* __restrict__ shift,
                                                 unsigned short* __restrict__ h0bf) {
    int tid = threadIdx.x;
    int f0 = tid * 4;
    float4 sc4 = *(const float4*)(scale + f0);
    float4 sh4 = *(const float4*)(shift + f0);
    float scv[4] = { sc4.x, sc4.y, sc4.z, sc4.w };
    float shv[4] = { sh4.x, sh4.y, sh4.z, sh4.w };
    size_t base = (size_t)blockIdx.x * 4 * F_ + f0;
#pragma unroll
    for (int r = 0; r < 4; r++) {
        ushort4 u = *(const ushort4*)(h0 + base + (size_t)r * F_);
        unsigned short uu[4] = { u.x, u.y, u.z, u.w };
        unsigned short ov[4];
#pragma unroll
        for (int j = 0; j < 4; j++)
            ov[j] = f2bf(swishf(scv[j] * bf2f(uu[j]) + shv[j]));
        *(ushort4*)(h0bf + base + (size_t)r * F_) = *(ushort4*)ov;
    }
}

// -------------------- gate logits via MFMA + fused per-row softmax --------------------
__global__ __launch_bounds__(256) void k_gates(const unsigned short* __restrict__ h0bf,
                                               const float* __restrict__ gate_w,
                                               const float* __restrict__ gate_b,
                                               float* __restrict__ gates) {
    __shared__ __align__(16) unsigned short gwt[16 * 1032];  // [col=t*8+e][f], +8 ushort pad
    int tid = threadIdx.x;
    for (int idx = tid; idx < 16 * 1024; idx += 256) {
        int col = idx >> 10, f = idx & 1023;
        int t = col >> 3, e = col & 7;
        gwt[col * 1032 + f] = f2bf(gate_w[(size_t)t * (F_ * E_) + (size_t)f * E_ + e]);
    }
    __syncthreads();
    int w = tid >> 6, lane = tid & 63;
    int l15 = lane & 15, quad = lane >> 4;
    int r0 = blockIdx.x * 128 + w * 32;
    f32x4 acc[2] = {};
    const unsigned short* a0p = h0bf + (size_t)(r0 + l15) * F_ + quad * 8;
    const unsigned short* a1p = a0p + (size_t)16 * F_;
    const unsigned short* wp = &gwt[l15 * 1032 + quad * 8];
#pragma unroll 4
    for (int k0 = 0; k0 < F_; k0 += 32) {
        bf16x8 wf  = *(const bf16x8*)(wp + k0);
        bf16x8 af0 = *(const bf16x8*)(a0p + k0);
        bf16x8 af1 = *(const bf16x8*)(a1p + k0);
        acc[0] = __builtin_amdgcn_mfma_f32_16x16x32_bf16(af0, wf, acc[0], 0, 0, 0);
        acc[1] = __builtin_amdgcn_mfma_f32_16x16x32_bf16(af1, wf, acc[1], 0, 0, 0);
    }
    float gb = gate_b[l15];
    int t = l15 >> 3, e = l15 & 7;
#pragma unroll
    for (int i = 0; i < 2; i++) {
#pragma unroll
        for (int reg = 0; reg < 4; reg++) {
            float v = acc[i][reg] + gb;
            float m = v;
            m = fmaxf(m, __shfl_xor(m, 1, 64));
            m = fmaxf(m, __shfl_xor(m, 2, 64));
            m = fmaxf(m, __shfl_xor(m, 4, 64));
            float ex = __expf(v - m);
            float s = ex;
            s += __shfl_xor(s, 1, 64);
            s += __shfl_xor(s, 2, 64);
            s += __shfl_xor(s, 4, 64);
            int row = r0 + i * 16 + quad * 4 + reg;
            gates[(size_t)t * (B_ * E_) + (size_t)row * E_ + e] = ex / s;
        }
    }
}

// -------------------- bf16 MFMA GEMM, 128x128, 2-phase double-buffered (T3 minimum recipe) ----
// stage t+1 issued BEFORE computing t; ONE drain+barrier per K-step (was two + full serial wait)
__global__ __launch_bounds__(256) void k_gemm_bf16(const unsigned short* __restrict__ A,
                                                   unsigned long long aslab,
                                                   const unsigned short* __restrict__ Wt,
                                                   unsigned long long wslab,
                                                   unsigned short* __restrict__ C,
                                                   unsigned long long cslab, int K,
                                                   float* __restrict__ psum,
                                                   float* __restrict__ psq) {
    __shared__ __align__(16) unsigned short As[2][128 * 32];
    __shared__ __align__(16) unsigned short Ws[2][128 * 32];
    int z = blockIdx.z;
    A  += (size_t)z * aslab;
    Wt += (size_t)z * wslab;
    C  += (size_t)z * cslab;
    const int N = gridDim.y * 128;
    int row0 = blockIdx.x * 128, col0 = blockIdx.y * 128;
    int tid = threadIdx.x;
    int w = tid >> 6, lane = tid & 63;
    int l15 = lane & 15, quad = lane >> 4;

    const unsigned short* ga0 = A  + (size_t)(row0 + w * 32 + (lane >> 2)) * K + (lane & 3) * 8;
    const unsigned short* ga1 = ga0 + 16 * (size_t)K;
    const unsigned short* gw0 = Wt + (size_t)(col0 + w * 32 + (lane >> 2)) * K + (lane & 3) * 8;
    const unsigned short* gw1 = gw0 + 16 * (size_t)K;
    int lo_a = (w * 32) * 32;
    int lo_w = (w * 32) * 32;

    int wm = (w & 1) * 64, wn = (w >> 1) * 64;

    f32x4 acc[4][4] = {};

#define STAGE_T(k0, b) do {                                   \
    gld16(ga0 + (k0), &As[b][lo_a]);                          \
    gld16(ga1 + (k0), &As[b][lo_a + 16 * 32]);                \
    gld16(gw0 + (k0), &Ws[b][lo_w]);                          \
    gld16(gw1 + (k0), &Ws[b][lo_w + 16 * 32]);                \
} while (0)

    STAGE_T(0, 0);
    __syncthreads();   // drains vmcnt+lgkmcnt, then barrier

    int nk = K >> 5;
    for (int t = 0; t < nk; t++) {
        int cur = t & 1;
        if (t + 1 < nk) STAGE_T((t + 1) * 32, cur ^ 1);
        const unsigned short* Afr = &As[cur][(wm + l15) * 32 + quad * 8];
        const unsigned short* Wfr = &Ws[cur][(wn + l15) * 32 + quad * 8];
        bf16x8 af[4], wf[4];
#pragma unroll
        for (int i = 0; i < 4; i++) af[i] = *(const bf16x8*)(Afr + i * 16 * 32);
#pragma unroll
        for (int j = 0; j < 4; j++) wf[j] = *(const bf16x8*)(Wfr + j * 16 * 32);
#pragma unroll
        for (int i = 0; i < 4; i++)
#pragma unroll
            for (int j = 0; j < 4; j++)
                acc[i][j] = __builtin_amdgcn_mfma_f32_16x16x32_bf16(af[i], wf[j], acc[i][j], 0, 0, 0);
        __syncthreads();   // next buf staged + everyone done reading cur
    }
#undef STAGE_T

#pragma unroll
    for (int i = 0; i < 4; i++) {
        int r = row0 + wm + i * 16 + quad * 4;
#pragma unroll
        for (int j = 0; j < 4; j++) {
            int cc = col0 + wn + j * 16 + l15;
            unsigned short* cp = C + (size_t)r * N + cc;
#pragma unroll
            for (int reg = 0; reg < 4; reg++)
                cp[(size_t)reg * N] = f2bf(acc[i][j][reg]);
        }
    }

    float* red = (float*)&As[0][0];
    float sj[4], qj[4];
#pragma unroll
    for (int j = 0; j < 4; j++) {
        float s = 0.f, q = 0.f;
#pragma unroll
        for (int i = 0; i < 4; i++)
#pragma unroll
            for (int reg = 0; reg < 4; reg++) {
                float v = acc[i][j][reg];
                s += v; q += v * v;
            }
        s += __shfl_down(s, 32, 64); s += __shfl_down(s, 16, 64);
        q += __shfl_down(q, 32, 64); q += __shfl_down(q, 16, 64);
        sj[j] = s; qj[j] = q;
    }
    if (lane < 16) {
#pragma unroll
        for (int j = 0; j < 4; j++) {
            int cib = wn + j * 16 + lane;
            red[cib * 2 + (w & 1)] = sj[j];
            red[256 + cib * 2 + (w & 1)] = qj[j];
        }
    }
    __syncthreads();
    if (tid < 128) {
        float s = red[tid * 2] + red[tid * 2 + 1];
        float q = red[256 + tid * 2] + red[256 + tid * 2 + 1];
        size_t row = (size_t)z * gridDim.x + blockIdx.x;
        psum[row * N + col0 + tid] = s;
        psq[row * N + col0 + tid] = q;
    }
}

// -------------------- 256x256 8-phase bf16 MFMA GEMM (T2+T3/T4+T5) + fused column stats ----------
__global__ __launch_bounds__(512, 2) void k_gemm256(const unsigned short* __restrict__ A,
                                                    const unsigned short* __restrict__ Wt,
                                                    unsigned short* __restrict__ Cc,
                                                    int N, int K,
                                                    float* __restrict__ psum,
                                                    float* __restrict__ psq) {
    __shared__ __align__(16) unsigned short lds[2][2][2][8192];  // [buf][A0/B1][half][128*64]
    int tid = threadIdx.x;
    int w = tid >> 6, lane = tid & 63;
    int l15 = lane & 15, quad = lane >> 4;
    int wm = w >> 2, wn = w & 3;

    // XCD-aware bijective swizzle (nwg % 8 == 0)
    int lin = blockIdx.y * gridDim.x + blockIdx.x;
    int cpx = (gridDim.x * gridDim.y) >> 3;
    int swz = (lin & 7) * cpx + (lin >> 3);
    int bx = swz & (gridDim.x - 1), by = swz / gridDim.x;
    int row0 = bx * 256, col0 = by * 256;

    // staging source (per-lane 16B granule, source-swizzled so linear LDS holds swizzled layout)
    int srow = tid >> 3, sperm = (tid & 7) ^ (srow & 7);
    const unsigned short* pA = A  + (size_t)(row0 + srow) * K + sperm * 8;
    const unsigned short* pB = Wt + (size_t)(col0 + srow) * K + sperm * 8;

    int aoffs[2];
#pragma unroll
    for (int kk = 0; kk < 2; kk++)
        aoffs[kk] = l15 * 64 + ((kk * 4 + quad) ^ (l15 & 7)) * 8;

    f32x4 acc[8][4] = {};
    bf16x8 afr[4][2], bfr[2][2];
    int nt = K >> 6;

#define STAGE256(t1, nb) do {                                                              \
    const unsigned short* sA = pA + (size_t)(t1) * 64;                                     \
    const unsigned short* sB = pB + (size_t)(t1) * 64;                                     \
    _Pragma("unroll")                                                                      \
    for (int h = 0; h < 2; h++)                                                            \
        _Pragma("unroll")                                                                  \
        for (int L = 0; L < 2; L++) {                                                      \
            gld16(sA + (size_t)(h * 128 + L * 64) * K, &lds[nb][0][h][w * 512 + L * 4096]);\
            gld16(sB + (size_t)(h * 128 + L * 64) * K, &lds[nb][1][h][w * 512 + L * 4096]);\
        }                                                                                  \
} while (0)

#define LDA256(mh) do {                                                                    \
    _Pragma("unroll")                                                                      \
    for (int mf = 0; mf < 4; mf++)                                                         \
        _Pragma("unroll")                                                                  \
        for (int kk = 0; kk < 2; kk++)                                                     \
            afr[mf][kk] = *(const bf16x8*)(Ab + ((mh) * 4 + mf) * 1024 + aoffs[kk]);       \
} while (0)

#define LDB256(nh) do {                                                                    \
    _Pragma("unroll")                                                                      \
    for (int nf = 0; nf < 2; nf++)                                                         \
        _Pragma("unroll")                                                                  \
        for (int kk = 0; kk < 2; kk++)                                                     \
            bfr[nf][kk] = *(const bf16x8*)(Bb + ((nh) * 2 + nf) * 1024 + aoffs[kk]);       \
} while (0)

#define MMA256(mh, nh) do {                                                                \
    _Pragma("unroll")                                                                      \
    for (int mf = 0; mf < 4; mf++)                                                         \
        _Pragma("unroll")                                                                  \
        for (int nf = 0; nf < 2; nf++)                                                     \
            _Pragma("unroll")                                                              \
            for (int kk = 0; kk < 2; kk++)                                                 \
                acc[(mh) * 4 + mf][(nh) * 2 + nf] = __builtin_amdgcn_mfma_f32_16x16x32_bf16(\
                    afr[mf][kk], bfr[nf][kk], acc[(mh) * 4 + mf][(nh) * 2 + nf], 0, 0, 0); \
} while (0)

#define PHASE_MID()                                                                        \
    __builtin_amdgcn_s_barrier();                                                          \
    asm volatile("s_waitcnt lgkmcnt(0)" ::: "memory");                                     \
    __builtin_amdgcn_sched_barrier(0);                                                     \
    __builtin_amdgcn_s_setprio(1);

#define PHASE_END()                                                                        \
    __builtin_amdgcn_s_setprio(0);                                                         \
    __builtin_amdgcn_sched_barrier(0);                                                     \
    __builtin_amdgcn_s_barrier();

    // prologue: tile 0 into buf 0
    STAGE256(0, 0);
    asm volatile("s_waitcnt vmcnt(0)" ::: "memory");
    __builtin_amdgcn_s_barrier();

    for (int t = 0; t < nt; t++) {
        int buf = t & 1;
        const unsigned short* Ab = &lds[buf][0][wm][0];
        const unsigned short* Bb = &lds[buf][1][wn >> 1][(wn & 1) * 4096];
        // phase 1: quadrant (0,0); burst-stage next tile into other buffer
        LDA256(0); LDB256(0);
        if (t + 1 < nt) STAGE256(t + 1, buf ^ 1);
        PHASE_MID();
        MMA256(0, 0);
        PHASE_END();
        // phase 2: quadrant (0,1) — reuse A(0)
        LDB256(1);
        PHASE_MID();
        MMA256(0, 1);
        PHASE_END();
        // phase 3: quadrant (1,1) — reuse B(1)
        LDA256(1);
        PHASE_MID();
        MMA256(1, 1);
        PHASE_END();
        // phase 4: quadrant (1,0); wait next tile's loads before handoff barrier
        LDB256(0);
        PHASE_MID();
        MMA256(1, 0);
        __builtin_amdgcn_s_setprio(0);
        __builtin_amdgcn_sched_barrier(0);
        asm volatile("s_waitcnt vmcnt(0)" ::: "memory");
        __builtin_amdgcn_s_barrier();
    }
#undef STAGE256
#undef LDA256
#undef LDB256
#undef MMA256
#undef PHASE_MID
#undef PHASE_END

    __syncthreads();

    // epilogue: bf16 C store (C/D layout: col=j*16+l15, row=quad*4+reg)
#pragma unroll
    for (int mf = 0; mf < 8; mf++) {
        int r = row0 + wm * 128 + mf * 16 + quad * 4;
#pragma unroll
        for (int nf = 0; nf < 4; nf++) {
            int cc = col0 + wn * 64 + nf * 16 + l15;
            unsigned short* cp = Cc + (size_t)r * N + cc;
#pragma unroll
            for (int reg = 0; reg < 4; reg++)
                cp[(size_t)reg * N] = f2bf(acc[mf][nf][reg]);
        }
    }

    // fused column partial stats over the block's 256 rows
    float* red = (float*)&lds[0][0][0][0];
    float* redq = red + 512;
    float sj[4], qj[4];
#pragma unroll
    for (int nf = 0; nf < 4; nf++) {
        float s = 0.f, q = 0.f;
#pragma unroll
        for (int mf = 0; mf < 8; mf++)
#pragma unroll
            for (int reg = 0; reg < 4; reg++) {
                float v = acc[mf][nf][reg];
                s += v; q += v * v;
            }
        s += __shfl_down(s, 32, 64); s += __shfl_down(s, 16, 64);
        q += __shfl_down(q, 32, 64); q += __shfl_down(q, 16, 64);
        sj[nf] = s; qj[nf] = q;
    }
    if (quad == 0) {
#pragma unroll
        for (int nf = 0; nf < 4; nf++) {
            int cib = wn * 64 + nf * 16 + l15;
            red[cib * 2 + wm] = sj[nf];
            redq[cib * 2 + wm] = qj[nf];
        }
    }
    __syncthreads();
    if (tid < 256) {
        float s = red[tid * 2] + red[tid * 2 + 1];
        float q = redq[tid * 2] + redq[tid * 2 + 1];
        psum[(size_t)bx * N + col0 + tid] = s;
        psq [(size_t)bx * N + col0 + tid] = q;
    }
}

// -------------------- expert BN+swish + gate mix -> mix bf16 [t][b][d] --------------------
__global__ __launch_bounds__(256) void k_mix(const unsigned short* __restrict__ eh,
                                             const float* __restrict__ scale,
                                             const float* __restrict__ shift,
                                             const float* __restrict__ gates,
                                             unsigned short* __restrict__ mix) {
    __shared__ float scl[E_ * D_], shl[E_ * D_];
    __shared__ float gl[2][2][8];
    int tid = threadIdx.x;
#pragma unroll
    for (int i = 0; i < 4; i++) {
        int li = tid + i * 256;
        ((float4*)scl)[li] = ((const float4*)scale)[li];
        ((float4*)shl)[li] = ((const float4*)shift)[li];
    }
    if (tid < 32) {
        int sub = tid >> 4, t = (tid >> 3) & 1, e = tid & 7;
        gl[sub][t][e] = gates[(size_t)t * (B_ * E_) + (size_t)(blockIdx.x * 2 + sub) * E_ + e];
    }
    __syncthreads();
    int sub = tid >> 7;
    int b = blockIdx.x * 2 + sub;
    int d0 = (tid & 127) * 4;
    float a0[4] = {0.f, 0.f, 0.f, 0.f}, a1[4] = {0.f, 0.f, 0.f, 0.f};
#pragma unroll
    for (int e = 0; e < E_; e++) {
        ushort4 u = *(const ushort4*)&eh[(size_t)b * (E_ * D_) + e * D_ + d0];
        float4 sc4 = *(const float4*)&scl[e * D_ + d0];
        float4 sh4 = *(const float4*)&shl[e * D_ + d0];
        float g0 = gl[sub][0][e], g1 = gl[sub][1][e];
        unsigned short uu[4] = { u.x, u.y, u.z, u.w };
        float scv[4] = { sc4.x, sc4.y, sc4.z, sc4.w };
        float shv[4] = { sh4.x, sh4.y, sh4.z, sh4.w };
#pragma unroll
        for (int l = 0; l < 4; l++) {
            float sw = swishf(scv[l] * bf2f(uu[l]) + shv[l]);
            a0[l] += g0 * sw;
            a1[l] += g1 * sw;
        }
    }
    unsigned short o0[4], o1[4];
#pragma unroll
    for (int l = 0; l < 4; l++) { o0[l] = f2bf(a0[l]); o1[l] = f2bf(a1[l]); }
    *(ushort4*)&mix[(size_t)b * D_ + d0] = *(ushort4*)o0;
    *(ushort4*)&mix[(size_t)(B_ * D_) + (size_t)b * D_ + d0] = *(ushort4*)o1;
}

// -------------------- task BN+swish + final heads, 8 batch rows per block --------------------
__global__ __launch_bounds__(256) void k_final(const unsigned short* __restrict__ th,
                                               const float* __restrict__ scale,
                                               const float* __restrict__ shift,
                                               const float* __restrict__ fwa,
                                               const float* __restrict__ fba,
                                               const float* __restrict__ fwb,
                                               const float* __restrict__ fbb,
                                               float* __restrict__ out) {
    __shared__ float t0[8][D_], t1[8][D_];
    __shared__ float pb[64];
    int tid = threadIdx.x;
    int b0 = blockIdx.x * 8;
#pragma unroll
    for (int t = 0; t < 2; t++) {
#pragma unroll
        for (int i = 0; i < 4; i++) {
            int li = tid + i * 256;
            int row = li >> 7, d = (li & 127) * 4;
            ushort4 u = *(const ushort4*)&th[((size_t)t * B_ + b0 + row) * D_ + d];
            unsigned short uu[4] = { u.x, u.y, u.z, u.w };
            float* dst = t ? &t1[row][d] : &t0[row][d];
#pragma unroll
            for (int l = 0; l < 4; l++)
                dst[l] = swishf(scale[t * D_ + d + l] * bf2f(uu[l]) + shift[t * D_ + d + l]);
        }
    }
    __syncthreads();
    // task a: 8 rows x 32 cols, 4 independent accumulators
    {
        int row = tid >> 5, col = tid & 31;
        float a0 = 0.f, a1 = 0.f, a2 = 0.f, a3 = 0.f;
        for (int d = 0; d < D_; d += 4) {
            a0 += t0[row][d + 0] * fwa[(d + 0) * 32 + col];
            a1 += t0[row][d + 1] * fwa[(d + 1) * 32 + col];
            a2 += t0[row][d + 2] * fwa[(d + 2) * 32 + col];
            a3 += t0[row][d + 3] * fwa[(d + 3) * 32 + col];
        }
        out[(size_t)(b0 + row) * OUTW + col] = fba[col] + ((a0 + a1) + (a2 + a3));
    }
    // task b: 8 rows x 2 cols, 4-way split over d
    if (tid < 64) {
        int row = tid >> 3, colb = (tid >> 2) & 1, part = tid & 3;
        float a = 0.f;
        for (int d = part * 128; d < part * 128 + 128; d += 2) {
            a += t1[row][d] * fwb[d * 2 + colb];
            a += t1[row][d + 1] * fwb[(d + 1) * 2 + colb];
        }
        pb[tid] = a;
    }
    __syncthreads();
    if (tid < 16) {
        int row = tid >> 1, colb = tid & 1;
        int base = row * 8 + colb * 4;
        float a = fbb[colb] + pb[base] + pb[base + 1] + pb[base + 2] + pb[base + 3];
        out[(size_t)(b0 + row) * OUTW + 32 + colb] = a;
    }
}

extern "C" void kernel_launch(void* const* d_in, const int* in_sizes, int n_in,
                              void* d_out, int out_size, void* d_ws, size_t ws_size,
                              hipStream_t stream) {
    const float* x        = (const float*)d_in[0];
    const float* w0       = (const float*)d_in[1];
    const float* b0       = (const float*)d_in[2];
    const float* bn0_g    = (const float*)d_in[3];
    const float* bn0_b    = (const float*)d_in[4];
    const float* gate_w   = (const float*)d_in[5];
    const float* gate_b   = (const float*)d_in[6];
    const float* exp_w    = (const float*)d_in[7];
    const float* exp_bn_g = (const float*)d_in[8];
    const float* exp_bn_b = (const float*)d_in[9];
    const float* task_w   = (const float*)d_in[10];
    const float* task_bn_g= (const float*)d_in[11];
    const float* task_bn_b= (const float*)d_in[12];
    const float* fwa      = (const float*)d_in[13];
    const float* fba      = (const float*)d_in[14];
    const float* fwb      = (const float*)d_in[15];
    const float* fbb      = (const float*)d_in[16];
    float* out = (float*)d_out;

    // workspace (float units). Aliases (disjoint lifetimes):
    //   thbf <- ehbf region (ehbf dead after k_mix)
    //   mixbf <- h0raw region (h0raw dead after k_bnswish)
    float* ws = (float*)d_ws;
    unsigned short* ehbf  = (unsigned short*)ws;              // B*E*D u16 (16,777,216 f)
    unsigned short* h0raw = (unsigned short*)(ws + 16777216); // B*F u16 (4,194,304 f)
    unsigned short* thbf  = ehbf;                             // T*B*D u16 (alias)
    unsigned short* mixbf = h0raw;                            // T*B*D u16 (alias)
    unsigned short* h0bf  = (unsigned short*)(ws + 20971520); // B*F u16 (4,194,304 f)
    unsigned short* wtE   = (unsigned short*)(ws + 25165824); // E*D*F u16 (2,097,152 f)
    unsigned short* twt   = (unsigned short*)(ws + 27262976); // T*D*D u16 (262,144 f)
    float* gates = ws + 27525120;                             // 131,072 f
    float* sc0   = ws + 27656192;
    float* sh0   = sc0 + 1024;
    float* scE   = sh0 + 1024;
    float* shE   = scE + 4096;
    float* scT   = shE + 4096;
    float* shT   = scT + 1024;
    float* psum  = shT + 1024;                                // 262,144 f
    float* psq   = psum + 262144;                             // 262,144 f

    // 0) weight transpose-converts (bf16, K-contiguous rows)
    k_wt<<<dim3(32, 16, 8), 256, 0, stream>>>(exp_w, wtE, F_, D_);   // [E][F][D] -> [E*D][F]
    k_wt<<<dim3(16, 16, 2), 256, 0, stream>>>(task_w, twt, D_, D_);  // [T][D][D] -> [T][D][D]^T
    // 1) split linear (bf16 MFMA, T14 pipelined staging) -> h0raw bf16 + fused BN0 partial stats
    k_split<<<dim3(64, 16), 256, 0, stream>>>(x, w0, b0, h0raw, psum, psq);
    k_stats_b<<<dim3(16, 1, 1), 64, 0, stream>>>(psum, psq, F_, 64, bn0_g, bn0_b, 0ull, sc0, sh0, 0ull);
    // 2) BN0 apply + swish -> h0bf (pure elementwise)
    k_bnswish<<<dim3(B_ / 4), 256, 0, stream>>>(h0raw, sc0, sh0, h0bf);
    // 2b) gate logits via MFMA + fused softmax -> gates
    k_gates<<<dim3(B_ / 128), 256, 0, stream>>>(h0bf, gate_w, gate_b, gates);
    // 3) expert GEMM (256x256 8-phase bf16 MFMA) -> ehbf + fused expert-BN partial stats
    k_gemm256<<<dim3(32, 16), 512, 0, stream>>>(h0bf, wtE, ehbf, E_ * D_, F_, psum, psq);
    k_stats_b<<<dim3(64, 1, 1), 64, 0, stream>>>(psum, psq, E_ * D_, 32, exp_bn_g, exp_bn_b, 0ull, scE, shE, 0ull);
    // 4) expert BN apply + swish + gate mix -> mixbf (bf16)
    k_mix<<<dim3(B_ / 2), 256, 0, stream>>>(ehbf, scE, shE, gates, mixbf);
    // 5) task GEMM (bf16 MFMA, 2-phase) -> thbf + fused task-BN partial stats
    k_gemm_bf16<<<dim3(64, 4, 2), 256, 0, stream>>>(mixbf, (unsigned long long)(B_ * D_),
                                                    twt, (unsigned long long)(D_ * D_),
                                                    thbf, (unsigned long long)(B_ * D_), D_,
                                                    psum, psq);
    k_stats_b<<<dim3(8, 1, 2), 64, 0, stream>>>(psum, psq, D_, 64, task_bn_g, task_bn_b, 512ull, scT, shT, 512ull);
    // 6) task BN apply + swish + final heads -> out [B, 34]
    k_final<<<dim3(B_ / 8), 256, 0, stream>>>(thbf, scT, shT, fwa, fba, fwb, fbb, out);
}

// Round 4
// 638.712 us; speedup vs baseline: 1.0246x; 1.0246x over previous
//
#include <hip/hip_runtime.h>
#include <math.h>

#define B_ 8192
#define IN_ 8000
#define C_ 16
#define S_ 500
#define O_ 64
#define F_ 1024
#define E_ 8
#define D_ 512
#define T_ 2
#define OUTW 34
#define EPS_ 1e-5f

typedef __attribute__((ext_vector_type(8))) short bf16x8;
typedef __attribute__((ext_vector_type(4))) float f32x4;

__device__ __forceinline__ float swishf(float x) {
    return x / (1.0f + __expf(-x));
}

// round-to-nearest-even f32 -> bf16 bits
__device__ __forceinline__ unsigned short f2bf(float f) {
    union { float f; unsigned u; } c;
    c.f = f;
    unsigned r = c.u + 0x7fffu + ((c.u >> 16) & 1u);
    return (unsigned short)(r >> 16);
}
__device__ __forceinline__ float bf2f(unsigned short b) {
    union { unsigned u; float f; } c;
    c.u = ((unsigned)b) << 16;
    return c.f;
}

// async global->LDS, 16B per lane; LDS dest is wave-uniform base + lane*16
__device__ __forceinline__ void gld16(const void* g, void* l) {
    __builtin_amdgcn_global_load_lds(
        (const __attribute__((address_space(1))) void*)g,
        (__attribute__((address_space(3))) void*)l, 16, 0, 0);
}

// -------------------- SplitLinear via bf16 MFMA + fused bias + BN0 partial stats --------------------
// (R2-known-good form: LDS-direct staging, cross-wave TLP hides latency)
__global__ __launch_bounds__(256) void k_split(const float* __restrict__ x,
                                               const float* __restrict__ w0,
                                               const float* __restrict__ b0,
                                               unsigned short* __restrict__ h0raw,
                                               float* __restrict__ psum,
                                               float* __restrict__ psq) {
    __shared__ __align__(16) unsigned short As[128 * 72];  // [row][72] padded
    __shared__ __align__(16) unsigned short Bs[64 * 72];
    int tid = threadIdx.x;
    int c = blockIdx.y;
    int brow0 = blockIdx.x * 128;
    const float* xp = x + (size_t)brow0 * IN_ + c * S_;
    const float* wp = w0 + (size_t)c * O_ * S_;

    int w = tid >> 6, lane = tid & 63;
    int l15 = lane & 15, quad = lane >> 4;
    int wm = w * 32;

    f32x4 acc[2][4] = {};

    for (int k0 = 0; k0 < 512; k0 += 64) {
        // stage A: 128 rows x 64 k (f32 -> bf16)
#pragma unroll
        for (int i = 0; i < 8; i++) {
            int li = tid + i * 256;
            int row = li >> 4, c4 = li & 15;
            int gk = k0 + c4 * 4;
            float4 v = make_float4(0.f, 0.f, 0.f, 0.f);
            if (gk + 3 < S_) v = *(const float4*)(xp + (size_t)row * IN_ + gk);
            unsigned short u[4] = { f2bf(v.x), f2bf(v.y), f2bf(v.z), f2bf(v.w) };
            *(ushort4*)&As[row * 72 + c4 * 4] = *(ushort4*)u;
        }
        // stage W: 64 rows x 64 k
#pragma unroll
        for (int i = 0; i < 4; i++) {
            int li = tid + i * 256;
            int row = li >> 4, c4 = li & 15;
            int gk = k0 + c4 * 4;
            float4 v = make_float4(0.f, 0.f, 0.f, 0.f);
            if (gk + 3 < S_) v = *(const float4*)(wp + (size_t)row * S_ + gk);
            unsigned short u[4] = { f2bf(v.x), f2bf(v.y), f2bf(v.z), f2bf(v.w) };
            *(ushort4*)&Bs[row * 72 + c4 * 4] = *(ushort4*)u;
        }
        __syncthreads();
#pragma unroll
        for (int kk = 0; kk < 64; kk += 32) {
            bf16x8 af[2], wf[4];
#pragma unroll
            for (int i = 0; i < 2; i++)
                af[i] = *(const bf16x8*)&As[(wm + i * 16 + l15) * 72 + kk + quad * 8];
#pragma unroll
            for (int j = 0; j < 4; j++)
                wf[j] = *(const bf16x8*)&Bs[(j * 16 + l15) * 72 + kk + quad * 8];
#pragma unroll
            for (int i = 0; i < 2; i++)
#pragma unroll
                for (int j = 0; j < 4; j++)
                    acc[i][j] = __builtin_amdgcn_mfma_f32_16x16x32_bf16(af[i], wf[j], acc[i][j], 0, 0, 0);
        }
        __syncthreads();
    }

    // epilogue: bias, bf16 store, column partial stats
    int colbase = c * O_;
    float sj[4], qj[4];
#pragma unroll
    for (int j = 0; j < 4; j++) {
        int col = j * 16 + l15;
        float bb = b0[colbase + col];
        float s = 0.f, q = 0.f;
#pragma unroll
        for (int i = 0; i < 2; i++) {
#pragma unroll
            for (int reg = 0; reg < 4; reg++) {
                float v = acc[i][j][reg] + bb;
                int rl = wm + i * 16 + quad * 4 + reg;
                h0raw[(size_t)(brow0 + rl) * F_ + colbase + col] = f2bf(v);
                s += v; q += v * v;
            }
        }
        s += __shfl_down(s, 32, 64); s += __shfl_down(s, 16, 64);
        q += __shfl_down(q, 32, 64); q += __shfl_down(q, 16, 64);
        sj[j] = s; qj[j] = q;
    }
    __syncthreads();
    float* red = (float*)As;
    if (lane < 16) {
#pragma unroll
        for (int j = 0; j < 4; j++) {
            int col = j * 16 + l15;
            red[col * 4 + w] = sj[j];
            red[256 + col * 4 + w] = qj[j];
        }
    }
    __syncthreads();
    if (tid < 64) {
        float ss = red[tid * 4] + red[tid * 4 + 1] + red[tid * 4 + 2] + red[tid * 4 + 3];
        float qq = red[256 + tid * 4] + red[256 + tid * 4 + 1] + red[256 + tid * 4 + 2] + red[256 + tid * 4 + 3];
        size_t idx = (size_t)blockIdx.x * F_ + colbase + tid;
        psum[idx] = ss; psq[idx] = qq;
    }
}

// -------------------- Column stats finalize --------------------
__global__ __launch_bounds__(64) void k_stats_b(const float* __restrict__ psum,
                                                const float* __restrict__ psq,
                                                int N, int YS,
                                                const float* __restrict__ g,
                                                const float* __restrict__ beta,
                                                unsigned long long gslab,
                                                float* __restrict__ scale,
                                                float* __restrict__ shift,
                                                unsigned long long oslab) {
    int n = blockIdx.x * 64 + threadIdx.x;
    int z = blockIdx.z;
    float s = 0.f, q = 0.f;
    for (int y = 0; y < YS; y++) {
        size_t idx = ((size_t)(z * YS + y)) * N + n;
        s += psum[idx]; q += psq[idx];
    }
    float mean = s * (1.0f / B_);
    float var = q * (1.0f / B_) - mean * mean;
    float sc = g[z * gslab + n] * rsqrtf(var + EPS_);
    scale[z * oslab + n] = sc;
    shift[z * oslab + n] = beta[z * gslab + n] - mean * sc;
}

// -------------------- merged transpose-convert (both weight tensors, one dispatch) ---------------
// z<8: exp_w [E][F][D] -> wtE [E*D][F]; z>=8: task_w [T][D][D] -> twt [T][D][D]^T
__global__ __launch_bounds__(256) void k_wt2(const float* __restrict__ exp_w,
                                             unsigned short* __restrict__ wtE,
                                             const float* __restrict__ task_w,
                                             unsigned short* __restrict__ twt) {
    int z = blockIdx.z;
    const float* ip; unsigned short* op; int K, N;
    if (z < 8) {
        K = F_; N = D_;
        ip = exp_w + (size_t)z * K * N;
        op = wtE + (size_t)z * N * K;
    } else {
        if (blockIdx.x >= 16) return;   // whole-block early exit, before any barrier
        K = D_; N = D_;
        int zz = z - 8;
        ip = task_w + (size_t)zz * K * N;
        op = twt + (size_t)zz * N * K;
    }
    __shared__ float t[32][33];
    int k0 = blockIdx.x * 32, n0 = blockIdx.y * 32;
    int tn = threadIdx.x & 31, tk = threadIdx.x >> 5;
#pragma unroll
    for (int p = 0; p < 4; p++) {
        int k = tk + p * 8;
        t[k][tn] = ip[(size_t)(k0 + k) * N + n0 + tn];
    }
    __syncthreads();
    int tk2 = threadIdx.x & 31, tn2 = threadIdx.x >> 5;
#pragma unroll
    for (int p = 0; p < 4; p++) {
        int n = tn2 + p * 8;
        op[(size_t)(n0 + n) * K + k0 + tk2] = f2bf(t[tk2][n]);
    }
}

// -------------------- fused BN0-apply + swish + gate MFMA + softmax --------------------
// grid 256 (32 rows/block), block 512 (8 waves). Phase 1: h0raw -> sw (regs) -> h0bf global +
// LDS stage. Phase 2: gate logits via MFMA from LDS, wave-split (2 row-slots x 4 K-quarters),
// partial sums in LDS. Phase 3: 32 threads do per-row softmax over 16 logits.
__global__ __launch_bounds__(512) void k_bng(const unsigned short* __restrict__ h0,
                                             const float* __restrict__ scale,
                                             const float* __restrict__ shift,
                                             const float* __restrict__ gate_w,
                                             const float* __restrict__ gate_b,
                                             unsigned short* __restrict__ h0bf,
                                             float* __restrict__ gates) {
    __shared__ __align__(16) unsigned short gwt[16 * 1032];  // [col=t*8+e][f], pad 8
    __shared__ __align__(16) unsigned short As[32 * 1032];   // [row][f] sw bf16, pad 8
    __shared__ float plog[4][32][16];                        // [kq][row][col]
    int tid = threadIdx.x;
    int brow = blockIdx.x * 32;
    // stage gate_w^T as bf16 (64 KB source, L2-hot after first blocks)
    for (int idx = tid; idx < 16 * 1024; idx += 512) {
        int col = idx >> 10, f = idx & 1023;
        int t = col >> 3, e = col & 7;
        gwt[col * 1032 + f] = f2bf(gate_w[(size_t)t * (F_ * E_) + (size_t)f * E_ + e]);
    }
    // phase 1: BN+swish, write h0bf + LDS
    int f0 = (tid & 255) * 4;
    int rh = tid >> 8;                 // row half: rows rh*16 .. rh*16+15
    float4 sc4 = *(const float4*)(scale + f0);
    float4 sh4 = *(const float4*)(shift + f0);
    float scv[4] = { sc4.x, sc4.y, sc4.z, sc4.w };
    float shv[4] = { sh4.x, sh4.y, sh4.z, sh4.w };
#pragma unroll
    for (int r = 0; r < 16; r++) {
        int row = rh * 16 + r;
        ushort4 u = *(const ushort4*)(h0 + (size_t)(brow + row) * F_ + f0);
        unsigned short uu[4] = { u.x, u.y, u.z, u.w };
        unsigned short ov[4];
#pragma unroll
        for (int j = 0; j < 4; j++)
            ov[j] = f2bf(swishf(scv[j] * bf2f(uu[j]) + shv[j]));
        *(ushort4*)(h0bf + (size_t)(brow + row) * F_ + f0) = *(ushort4*)ov;
        *(ushort4*)&As[row * 1032 + f0] = *(ushort4*)ov;
    }
    __syncthreads();
    // phase 2: gate MFMA; wave w -> (row slot, K quarter)
    int w = tid >> 6, lane = tid & 63;
    int l15 = lane & 15, quad = lane >> 4;
    int slot = w & 1, kq = w >> 1;
    f32x4 acc = {};
    const unsigned short* ap = &As[(slot * 16 + l15) * 1032 + kq * 256 + quad * 8];
    const unsigned short* wp = &gwt[l15 * 1032 + kq * 256 + quad * 8];
#pragma unroll
    for (int k0 = 0; k0 < 256; k0 += 32) {
        bf16x8 af = *(const bf16x8*)(ap + k0);
        bf16x8 wf = *(const bf16x8*)(wp + k0);
        acc = __builtin_amdgcn_mfma_f32_16x16x32_bf16(af, wf, acc, 0, 0, 0);
    }
    // C layout: col=l15, row=quad*4+reg (within slot)
#pragma unroll
    for (int reg = 0; reg < 4; reg++)
        plog[kq][slot * 16 + quad * 4 + reg][l15] = acc[reg];
    __syncthreads();
    // phase 3: per-row softmax over (t,e)
    if (tid < 32) {
        int r = tid;
        float lg[16];
#pragma unroll
        for (int c = 0; c < 16; c++)
            lg[c] = plog[0][r][c] + plog[1][r][c] + plog[2][r][c] + plog[3][r][c] + gate_b[c];
#pragma unroll
        for (int t = 0; t < 2; t++) {
            float mx = -1e30f;
#pragma unroll
            for (int e = 0; e < 8; e++) mx = fmaxf(mx, lg[t * 8 + e]);
            float ex[8], s = 0.f;
#pragma unroll
            for (int e = 0; e < 8; e++) { ex[e] = __expf(lg[t * 8 + e] - mx); s += ex[e]; }
            float inv = 1.0f / s;
#pragma unroll
            for (int e = 0; e < 8; e++)
                gates[(size_t)t * (B_ * E_) + (size_t)(brow + r) * E_ + e] = ex[e] * inv;
        }
    }
}

// -------------------- bf16 MFMA GEMM + fused column partial stats, bf16 C (128x128, R2 form) ----
__global__ __launch_bounds__(256) void k_gemm_bf16(const unsigned short* __restrict__ A,
                                                   unsigned long long aslab,
                                                   const unsigned short* __restrict__ Wt,
                                                   unsigned long long wslab,
                                                   unsigned short* __restrict__ C,
                                                   unsigned long long cslab, int K,
                                                   float* __restrict__ psum,
                                                   float* __restrict__ psq) {
    __shared__ __align__(16) unsigned short As[128 * 32];
    __shared__ __align__(16) unsigned short Ws[128 * 32];
    int z = blockIdx.z;
    A  += (size_t)z * aslab;
    Wt += (size_t)z * wslab;
    C  += (size_t)z * cslab;
    const int N = gridDim.y * 128;
    int row0 = blockIdx.x * 128, col0 = blockIdx.y * 128;
    int tid = threadIdx.x;
    int w = tid >> 6, lane = tid & 63;
    int l15 = lane & 15, quad = lane >> 4;

    const unsigned short* ga0 = A  + (size_t)(row0 + w * 32 + (lane >> 2)) * K + (lane & 3) * 8;
    const unsigned short* ga1 = ga0 + 16 * (size_t)K;
    const unsigned short* gw0 = Wt + (size_t)(col0 + w * 32 + (lane >> 2)) * K + (lane & 3) * 8;
    const unsigned short* gw1 = gw0 + 16 * (size_t)K;
    unsigned short* la0 = As + (w * 32) * 32;
    unsigned short* la1 = As + (w * 32 + 16) * 32;
    unsigned short* lw0 = Ws + (w * 32) * 32;
    unsigned short* lw1 = Ws + (w * 32 + 16) * 32;

    int wm = (w & 1) * 64, wn = (w >> 1) * 64;
    const unsigned short* Afr = As + (size_t)(wm + l15) * 32 + quad * 8;
    const unsigned short* Wfr = Ws + (size_t)(wn + l15) * 32 + quad * 8;

    f32x4 acc[4][4] = {};

    for (int k0 = 0; k0 < K; k0 += 32) {
        gld16(ga0 + k0, la0);
        gld16(ga1 + k0, la1);
        gld16(gw0 + k0, lw0);
        gld16(gw1 + k0, lw1);
        __syncthreads();
        bf16x8 af[4], wf[4];
#pragma unroll
        for (int i = 0; i < 4; i++) af[i] = *(const bf16x8*)(Afr + i * 16 * 32);
#pragma unroll
        for (int j = 0; j < 4; j++) wf[j] = *(const bf16x8*)(Wfr + j * 16 * 32);
#pragma unroll
        for (int i = 0; i < 4; i++)
#pragma unroll
            for (int j = 0; j < 4; j++)
                acc[i][j] = __builtin_amdgcn_mfma_f32_16x16x32_bf16(af[i], wf[j], acc[i][j], 0, 0, 0);
        __syncthreads();
    }

#pragma unroll
    for (int i = 0; i < 4; i++) {
        int r = row0 + wm + i * 16 + quad * 4;
#pragma unroll
        for (int j = 0; j < 4; j++) {
            int cc = col0 + wn + j * 16 + l15;
            unsigned short* cp = C + (size_t)r * N + cc;
#pragma unroll
            for (int reg = 0; reg < 4; reg++)
                cp[(size_t)reg * N] = f2bf(acc[i][j][reg]);
        }
    }

    float* red = (float*)As;
    float sj[4], qj[4];
#pragma unroll
    for (int j = 0; j < 4; j++) {
        float s = 0.f, q = 0.f;
#pragma unroll
        for (int i = 0; i < 4; i++)
#pragma unroll
            for (int reg = 0; reg < 4; reg++) {
                float v = acc[i][j][reg];
                s += v; q += v * v;
            }
        s += __shfl_down(s, 32, 64); s += __shfl_down(s, 16, 64);
        q += __shfl_down(q, 32, 64); q += __shfl_down(q, 16, 64);
        sj[j] = s; qj[j] = q;
    }
    if (lane < 16) {
#pragma unroll
        for (int j = 0; j < 4; j++) {
            int cib = wn + j * 16 + lane;
            red[cib * 2 + (w & 1)] = sj[j];
            red[256 + cib * 2 + (w & 1)] = qj[j];
        }
    }
    __syncthreads();
    if (tid < 128) {
        float s = red[tid * 2] + red[tid * 2 + 1];
        float q = red[256 + tid * 2] + red[256 + tid * 2 + 1];
        size_t row = (size_t)z * gridDim.x + blockIdx.x;
        psum[row * N + col0 + tid] = s;
        psq[row * N + col0 + tid] = q;
    }
}

// -------------------- 256x256 8-phase bf16 MFMA GEMM (T2+T3/T4+T5) + fused column stats ----------
__global__ __launch_bounds__(512, 2) void k_gemm256(const unsigned short* __restrict__ A,
                                                    const unsigned short* __restrict__ Wt,
                                                    unsigned short* __restrict__ Cc,
                                                    int N, int K,
                                                    float* __restrict__ psum,
                                                    float* __restrict__ psq) {
    __shared__ __align__(16) unsigned short lds[2][2][2][8192];  // [buf][A0/B1][half][128*64]
    int tid = threadIdx.x;
    int w = tid >> 6, lane = tid & 63;
    int l15 = lane & 15, quad = lane >> 4;
    int wm = w >> 2, wn = w & 3;

    // XCD-aware bijective swizzle (nwg % 8 == 0)
    int lin = blockIdx.y * gridDim.x + blockIdx.x;
    int cpx = (gridDim.x * gridDim.y) >> 3;
    int swz = (lin & 7) * cpx + (lin >> 3);
    int bx = swz & (gridDim.x - 1), by = swz / gridDim.x;
    int row0 = bx * 256, col0 = by * 256;

    // staging source (per-lane 16B granule, source-swizzled so linear LDS holds swizzled layout)
    int srow = tid >> 3, sperm = (tid & 7) ^ (srow & 7);
    const unsigned short* pA = A  + (size_t)(row0 + srow) * K + sperm * 8;
    const unsigned short* pB = Wt + (size_t)(col0 + srow) * K + sperm * 8;

    int aoffs[2];
#pragma unroll
    for (int kk = 0; kk < 2; kk++)
        aoffs[kk] = l15 * 64 + ((kk * 4 + quad) ^ (l15 & 7)) * 8;

    f32x4 acc[8][4] = {};
    bf16x8 afr[4][2], bfr[2][2];
    int nt = K >> 6;

#define STAGE256(t1, nb) do {                                                              \
    const unsigned short* sA = pA + (size_t)(t1) * 64;                                     \
    const unsigned short* sB = pB + (size_t)(t1) * 64;                                     \
    _Pragma("unroll")                                                                      \
    for (int h = 0; h < 2; h++)                                                            \
        _Pragma("unroll")                                                                  \
        for (int L = 0; L < 2; L++) {                                                      \
            gld16(sA + (size_t)(h * 128 + L * 64) * K, &lds[nb][0][h][w * 512 + L * 4096]);\
            gld16(sB + (size_t)(h * 128 + L * 64) * K, &lds[nb][1][h][w * 512 + L * 4096]);\
        }                                                                                  \
} while (0)

#define LDA256(mh) do {                                                                    \
    _Pragma("unroll")                                                                      \
    for (int mf = 0; mf < 4; mf++)                                                         \
        _Pragma("unroll")                                                                  \
        for (int kk = 0; kk < 2; kk++)                                                     \
            afr[mf][kk] = *(const bf16x8*)(Ab + ((mh) * 4 + mf) * 1024 + aoffs[kk]);       \
} while (0)

#define LDB256(nh) do {                                                                    \
    _Pragma("unroll")                                                                      \
    for (int nf = 0; nf < 2; nf++)                                                         \
        _Pragma("unroll")                                                                  \
        for (int kk = 0; kk < 2; kk++)                                                     \
            bfr[nf][kk] = *(const bf16x8*)(Bb + ((nh) * 2 + nf) * 1024 + aoffs[kk]);       \
} while (0)

#define MMA256(mh, nh) do {                                                                \
    _Pragma("unroll")                                                                      \
    for (int mf = 0; mf < 4; mf++)                                                         \
        _Pragma("unroll")                                                                  \
        for (int nf = 0; nf < 2; nf++)                                                     \
            _Pragma("unroll")                                                              \
            for (int kk = 0; kk < 2; kk++)                                                 \
                acc[(mh) * 4 + mf][(nh) * 2 + nf] = __builtin_amdgcn_mfma_f32_16x16x32_bf16(\
                    afr[mf][kk], bfr[nf][kk], acc[(mh) * 4 + mf][(nh) * 2 + nf], 0, 0, 0); \
} while (0)

#define PHASE_MID()                                                                        \
    __builtin_amdgcn_s_barrier();                                                          \
    asm volatile("s_waitcnt lgkmcnt(0)" ::: "memory");                                     \
    __builtin_amdgcn_sched_barrier(0);                                                     \
    __builtin_amdgcn_s_setprio(1);

#define PHASE_END()                                                                        \
    __builtin_amdgcn_s_setprio(0);                                                         \
    __builtin_amdgcn_sched_barrier(0);                                                     \
    __builtin_amdgcn_s_barrier();

    // prologue: tile 0 into buf 0
    STAGE256(0, 0);
    asm volatile("s_waitcnt vmcnt(0)" ::: "memory");
    __builtin_amdgcn_s_barrier();

    for (int t = 0; t < nt; t++) {
        int buf = t & 1;
        const unsigned short* Ab = &lds[buf][0][wm][0];
        const unsigned short* Bb = &lds[buf][1][wn >> 1][(wn & 1) * 4096];
        // phase 1: quadrant (0,0); burst-stage next tile into other buffer
        LDA256(0); LDB256(0);
        if (t + 1 < nt) STAGE256(t + 1, buf ^ 1);
        PHASE_MID();
        MMA256(0, 0);
        PHASE_END();
        // phase 2: quadrant (0,1) — reuse A(0)
        LDB256(1);
        PHASE_MID();
        MMA256(0, 1);
        PHASE_END();
        // phase 3: quadrant (1,1) — reuse B(1)
        LDA256(1);
        PHASE_MID();
        MMA256(1, 1);
        PHASE_END();
        // phase 4: quadrant (1,0); wait next tile's loads before handoff barrier
        LDB256(0);
        PHASE_MID();
        MMA256(1, 0);
        __builtin_amdgcn_s_setprio(0);
        __builtin_amdgcn_sched_barrier(0);
        asm volatile("s_waitcnt vmcnt(0)" ::: "memory");
        __builtin_amdgcn_s_barrier();
    }
#undef STAGE256
#undef LDA256
#undef LDB256
#undef MMA256
#undef PHASE_MID
#undef PHASE_END

    __syncthreads();

    // epilogue: bf16 C store (C/D layout: col=j*16+l15, row=quad*4+reg)
#pragma unroll
    for (int mf = 0; mf < 8; mf++) {
        int r = row0 + wm * 128 + mf * 16 + quad * 4;
#pragma unroll
        for (int nf = 0; nf < 4; nf++) {
            int cc = col0 + wn * 64 + nf * 16 + l15;
            unsigned short* cp = Cc + (size_t)r * N + cc;
#pragma unroll
            for (int reg = 0; reg < 4; reg++)
                cp[(size_t)reg * N] = f2bf(acc[mf][nf][reg]);
        }
    }

    // fused column partial stats over the block's 256 rows
    float* red = (float*)&lds[0][0][0][0];
    float* redq = red + 512;
    float sj[4], qj[4];
#pragma unroll
    for (int nf = 0; nf < 4; nf++) {
        float s = 0.f, q = 0.f;
#pragma unroll
        for (int mf = 0; mf < 8; mf++)
#pragma unroll
            for (int reg = 0; reg < 4; reg++) {
                float v = acc[mf][nf][reg];
                s += v; q += v * v;
            }
        s += __shfl_down(s, 32, 64); s += __shfl_down(s, 16, 64);
        q += __shfl_down(q, 32, 64); q += __shfl_down(q, 16, 64);
        sj[nf] = s; qj[nf] = q;
    }
    if (quad == 0) {
#pragma unroll
        for (int nf = 0; nf < 4; nf++) {
            int cib = wn * 64 + nf * 16 + l15;
            red[cib * 2 + wm] = sj[nf];
            redq[cib * 2 + wm] = qj[nf];
        }
    }
    __syncthreads();
    if (tid < 256) {
        float s = red[tid * 2] + red[tid * 2 + 1];
        float q = redq[tid * 2] + redq[tid * 2 + 1];
        psum[(size_t)bx * N + col0 + tid] = s;
        psq [(size_t)bx * N + col0 + tid] = q;
    }
}

// -------------------- expert BN+swish + gate mix -> mix bf16 [t][b][d] --------------------
__global__ __launch_bounds__(256) void k_mix(const unsigned short* __restrict__ eh,
                                             const float* __restrict__ scale,
                                             const float* __restrict__ shift,
                                             const float* __restrict__ gates,
                                             unsigned short* __restrict__ mix) {
    __shared__ float scl[E_ * D_], shl[E_ * D_];
    __shared__ float gl[2][2][8];
    int tid = threadIdx.x;
#pragma unroll
    for (int i = 0; i < 4; i++) {
        int li = tid + i * 256;
        ((float4*)scl)[li] = ((const float4*)scale)[li];
        ((float4*)shl)[li] = ((const float4*)shift)[li];
    }
    if (tid < 32) {
        int sub = tid >> 4, t = (tid >> 3) & 1, e = tid & 7;
        gl[sub][t][e] = gates[(size_t)t * (B_ * E_) + (size_t)(blockIdx.x * 2 + sub) * E_ + e];
    }
    __syncthreads();
    int sub = tid >> 7;
    int b = blockIdx.x * 2 + sub;
    int d0 = (tid & 127) * 4;
    float a0[4] = {0.f, 0.f, 0.f, 0.f}, a1[4] = {0.f, 0.f, 0.f, 0.f};
#pragma unroll
    for (int e = 0; e < E_; e++) {
        ushort4 u = *(const ushort4*)&eh[(size_t)b * (E_ * D_) + e * D_ + d0];
        float4 sc4 = *(const float4*)&scl[e * D_ + d0];
        float4 sh4 = *(const float4*)&shl[e * D_ + d0];
        float g0 = gl[sub][0][e], g1 = gl[sub][1][e];
        unsigned short uu[4] = { u.x, u.y, u.z, u.w };
        float scv[4] = { sc4.x, sc4.y, sc4.z, sc4.w };
        float shv[4] = { sh4.x, sh4.y, sh4.z, sh4.w };
#pragma unroll
        for (int l = 0; l < 4; l++) {
            float sw = swishf(scv[l] * bf2f(uu[l]) + shv[l]);
            a0[l] += g0 * sw;
            a1[l] += g1 * sw;
        }
    }
    unsigned short o0[4], o1[4];
#pragma unroll
    for (int l = 0; l < 4; l++) { o0[l] = f2bf(a0[l]); o1[l] = f2bf(a1[l]); }
    *(ushort4*)&mix[(size_t)b * D_ + d0] = *(ushort4*)o0;
    *(ushort4*)&mix[(size_t)(B_ * D_) + (size_t)b * D_ + d0] = *(ushort4*)o1;
}

// -------------------- task BN+swish + final heads, 8 batch rows per block (R2 form) --------------
__global__ __launch_bounds__(256) void k_final(const unsigned short* __restrict__ th,
                                               const float* __restrict__ scale,
                                               const float* __restrict__ shift,
                                               const float* __restrict__ fwa,
                                               const float* __restrict__ fba,
                                               const float* __restrict__ fwb,
                                               const float* __restrict__ fbb,
                                               float* __restrict__ out) {
    __shared__ float t0[8][D_], t1[8][D_];
    __shared__ float pb[64];
    int tid = threadIdx.x;
    int b0 = blockIdx.x * 8;
#pragma unroll
    for (int t = 0; t < 2; t++) {
#pragma unroll
        for (int i = 0; i < 4; i++) {
            int li = tid + i * 256;
            int row = li >> 7, d = (li & 127) * 4;
            ushort4 u = *(const ushort4*)&th[((size_t)t * B_ + b0 + row) * D_ + d];
            unsigned short uu[4] = { u.x, u.y, u.z, u.w };
            float* dst = t ? &t1[row][d] : &t0[row][d];
#pragma unroll
            for (int l = 0; l < 4; l++)
                dst[l] = swishf(scale[t * D_ + d + l] * bf2f(uu[l]) + shift[t * D_ + d + l]);
        }
    }
    __syncthreads();
    // task a: 8 rows x 32 cols
    {
        int row = tid >> 5, col = tid & 31;
        float acc = fba[col];
        for (int d = 0; d < D_; d++) acc += t0[row][d] * fwa[d * 32 + col];
        out[(size_t)(b0 + row) * OUTW + col] = acc;
    }
    // task b: 8 rows x 2 cols, 4-way split over d
    if (tid < 64) {
        int row = tid >> 3, colb = (tid >> 2) & 1, part = tid & 3;
        float a = 0.f;
        for (int d = part * 128; d < part * 128 + 128; d++) a += t1[row][d] * fwb[d * 2 + colb];
        pb[tid] = a;
    }
    __syncthreads();
    if (tid < 16) {
        int row = tid >> 1, colb = tid & 1;
        int base = row * 8 + colb * 4;
        float a = fbb[colb] + pb[base] + pb[base + 1] + pb[base + 2] + pb[base + 3];
        out[(size_t)(b0 + row) * OUTW + 32 + colb] = a;
    }
}

extern "C" void kernel_launch(void* const* d_in, const int* in_sizes, int n_in,
                              void* d_out, int out_size, void* d_ws, size_t ws_size,
                              hipStream_t stream) {
    const float* x        = (const float*)d_in[0];
    const float* w0       = (const float*)d_in[1];
    const float* b0       = (const float*)d_in[2];
    const float* bn0_g    = (const float*)d_in[3];
    const float* bn0_b    = (const float*)d_in[4];
    const float* gate_w   = (const float*)d_in[5];
    const float* gate_b   = (const float*)d_in[6];
    const float* exp_w    = (const float*)d_in[7];
    const float* exp_bn_g = (const float*)d_in[8];
    const float* exp_bn_b = (const float*)d_in[9];
    const float* task_w   = (const float*)d_in[10];
    const float* task_bn_g= (const float*)d_in[11];
    const float* task_bn_b= (const float*)d_in[12];
    const float* fwa      = (const float*)d_in[13];
    const float* fba      = (const float*)d_in[14];
    const float* fwb      = (const float*)d_in[15];
    const float* fbb      = (const float*)d_in[16];
    float* out = (float*)d_out;

    // workspace (float units). Aliases (disjoint lifetimes):
    //   thbf <- ehbf region (ehbf dead after k_mix)
    //   mixbf <- h0raw region (h0raw dead after k_bng)
    float* ws = (float*)d_ws;
    unsigned short* ehbf  = (unsigned short*)ws;              // B*E*D u16 (16,777,216 f)
    unsigned short* h0raw = (unsigned short*)(ws + 16777216); // B*F u16 (4,194,304 f)
    unsigned short* thbf  = ehbf;                             // T*B*D u16 (alias)
    unsigned short* mixbf = h0raw;                            // T*B*D u16 (alias)
    unsigned short* h0bf  = (unsigned short*)(ws + 20971520); // B*F u16 (4,194,304 f)
    unsigned short* wtE   = (unsigned short*)(ws + 25165824); // E*D*F u16 (2,097,152 f)
    unsigned short* twt   = (unsigned short*)(ws + 27262976); // T*D*D u16 (262,144 f)
    float* gates = ws + 27525120;                             // 131,072 f
    float* sc0   = ws + 27656192;
    float* sh0   = sc0 + 1024;
    float* scE   = sh0 + 1024;
    float* shE   = scE + 4096;
    float* scT   = shE + 4096;
    float* shT   = scT + 1024;
    float* psum  = shT + 1024;                                // 262,144 f
    float* psq   = psum + 262144;                             // 262,144 f

    // 0) merged weight transpose-converts (bf16, K-contiguous rows)
    k_wt2<<<dim3(32, 16, 10), 256, 0, stream>>>(exp_w, wtE, task_w, twt);
    // 1) split linear (bf16 MFMA) -> h0raw bf16 + fused BN0 partial stats
    k_split<<<dim3(64, 16), 256, 0, stream>>>(x, w0, b0, h0raw, psum, psq);
    k_stats_b<<<dim3(16, 1, 1), 64, 0, stream>>>(psum, psq, F_, 64, bn0_g, bn0_b, 0ull, sc0, sh0, 0ull);
    // 2) fused BN0 apply + swish + gate MFMA + softmax -> h0bf, gates
    k_bng<<<dim3(256), 512, 0, stream>>>(h0raw, sc0, sh0, gate_w, gate_b, h0bf, gates);
    // 3) expert GEMM (256x256 8-phase bf16 MFMA) -> ehbf + fused expert-BN partial stats
    k_gemm256<<<dim3(32, 16), 512, 0, stream>>>(h0bf, wtE, ehbf, E_ * D_, F_, psum, psq);
    k_stats_b<<<dim3(64, 1, 1), 64, 0, stream>>>(psum, psq, E_ * D_, 32, exp_bn_g, exp_bn_b, 0ull, scE, shE, 0ull);
    // 4) expert BN apply + swish + gate mix -> mixbf (bf16)
    k_mix<<<dim3(B_ / 2), 256, 0, stream>>>(ehbf, scE, shE, gates, mixbf);
    // 5) task GEMM (bf16 MFMA) -> thbf + fused task-BN partial stats
    k_gemm_bf16<<<dim3(64, 4, 2), 256, 0, stream>>>(mixbf, (unsigned long long)(B_ * D_),
                                                    twt, (unsigned long long)(D_ * D_),
                                                    thbf, (unsigned long long)(B_ * D_), D_,
                                                    psum, psq);
    k_stats_b<<<dim3(8, 1, 2), 64, 0, stream>>>(psum, psq, D_, 64, task_bn_g, task_bn_b, 512ull, scT, shT, 512ull);
    // 6) task BN apply + swish + final heads -> out [B, 34]
    k_final<<<dim3(B_ / 8), 256, 0, stream>>>(thbf, scT, shT, fwa, fba, fwb, fbb, out);
}

// Round 5
// 631.606 us; speedup vs baseline: 1.0362x; 1.0113x over previous
//
#include <hip/hip_runtime.h>
#include <math.h>

#define B_ 8192
#define IN_ 8000
#define C_ 16
#define S_ 500
#define O_ 64
#define F_ 1024
#define E_ 8
#define D_ 512
#define T_ 2
#define OUTW 34
#define EPS_ 1e-5f

typedef __attribute__((ext_vector_type(8))) short bf16x8;
typedef __attribute__((ext_vector_type(4))) float f32x4;

__device__ __forceinline__ float swishf(float x) {
    return x / (1.0f + __expf(-x));
}

// round-to-nearest-even f32 -> bf16 bits
__device__ __forceinline__ unsigned short f2bf(float f) {
    union { float f; unsigned u; } c;
    c.f = f;
    unsigned r = c.u + 0x7fffu + ((c.u >> 16) & 1u);
    return (unsigned short)(r >> 16);
}
__device__ __forceinline__ float bf2f(unsigned short b) {
    union { unsigned u; float f; } c;
    c.u = ((unsigned)b) << 16;
    return c.f;
}

// async global->LDS, 16B per lane; LDS dest is wave-uniform base + lane*16
__device__ __forceinline__ void gld16(const void* g, void* l) {
    __builtin_amdgcn_global_load_lds(
        (const __attribute__((address_space(1))) void*)g,
        (__attribute__((address_space(3))) void*)l, 16, 0, 0);
}

// -------------------- k_pre: merged weight transposes + SplitLinear MFMA + ctr zero -------------
// bid < 1024: split-linear block (bx = bid&63, c = bid>>6), R2-proven form.
// bid >= 1024: transpose-convert blocks (4096 for exp_w, 512 for task_w); first one zeroes ctrs.
__global__ __launch_bounds__(256) void k_pre(const float* __restrict__ x,
                                             const float* __restrict__ w0,
                                             const float* __restrict__ b0,
                                             unsigned short* __restrict__ h0raw,
                                             float* __restrict__ psum,
                                             float* __restrict__ psq,
                                             const float* __restrict__ exp_w,
                                             unsigned short* __restrict__ wtE,
                                             const float* __restrict__ task_w,
                                             unsigned short* __restrict__ twt,
                                             unsigned* __restrict__ ctrs) {
    __shared__ __align__(16) unsigned short As[128 * 72];  // [row][72] padded
    __shared__ __align__(16) unsigned short Bs[64 * 72];
    __shared__ float tt[32][33];
    int tid = threadIdx.x;
    int bid = blockIdx.x;

    if (bid >= 1024) {
        int wid = bid - 1024;
        if (wid == 0 && tid == 0) { ctrs[0] = 0u; ctrs[1] = 0u; }
        const float* ip; unsigned short* op; int K, N, k0, n0;
        if (wid < 4096) {               // exp_w [E][F][D] -> wtE [E*D][F]
            int xx = wid & 31, yy = (wid >> 5) & 15, z = wid >> 9;
            K = F_; N = D_;
            ip = exp_w + (size_t)z * K * N;
            op = wtE + (size_t)z * N * K;
            k0 = xx * 32; n0 = yy * 32;
        } else {                        // task_w [T][D][D] -> twt [T][D][D]^T
            int w2 = wid - 4096;
            int xx = w2 & 15, yy = (w2 >> 4) & 15, z = w2 >> 8;
            K = D_; N = D_;
            ip = task_w + (size_t)z * K * N;
            op = twt + (size_t)z * N * K;
            k0 = xx * 32; n0 = yy * 32;
        }
        int tn = tid & 31, tk = tid >> 5;
#pragma unroll
        for (int p = 0; p < 4; p++) {
            int k = tk + p * 8;
            tt[k][tn] = ip[(size_t)(k0 + k) * N + n0 + tn];
        }
        __syncthreads();
#pragma unroll
        for (int p = 0; p < 4; p++) {
            int n = tk + p * 8;
            op[(size_t)(n0 + n) * K + k0 + tn] = f2bf(tt[tn][n]);
        }
        return;
    }

    // ---- split-linear part ----
    int bx = bid & 63, c = bid >> 6;
    int brow0 = bx * 128;
    const float* xp = x + (size_t)brow0 * IN_ + c * S_;
    const float* wp = w0 + (size_t)c * O_ * S_;

    int w = tid >> 6, lane = tid & 63;
    int l15 = lane & 15, quad = lane >> 4;
    int wm = w * 32;

    f32x4 acc[2][4] = {};

    for (int k0 = 0; k0 < 512; k0 += 64) {
        // stage A: 128 rows x 64 k (f32 -> bf16)
#pragma unroll
        for (int i = 0; i < 8; i++) {
            int li = tid + i * 256;
            int row = li >> 4, c4 = li & 15;
            int gk = k0 + c4 * 4;
            float4 v = make_float4(0.f, 0.f, 0.f, 0.f);
            if (gk + 3 < S_) v = *(const float4*)(xp + (size_t)row * IN_ + gk);
            unsigned short u[4] = { f2bf(v.x), f2bf(v.y), f2bf(v.z), f2bf(v.w) };
            *(ushort4*)&As[row * 72 + c4 * 4] = *(ushort4*)u;
        }
        // stage W: 64 rows x 64 k
#pragma unroll
        for (int i = 0; i < 4; i++) {
            int li = tid + i * 256;
            int row = li >> 4, c4 = li & 15;
            int gk = k0 + c4 * 4;
            float4 v = make_float4(0.f, 0.f, 0.f, 0.f);
            if (gk + 3 < S_) v = *(const float4*)(wp + (size_t)row * S_ + gk);
            unsigned short u[4] = { f2bf(v.x), f2bf(v.y), f2bf(v.z), f2bf(v.w) };
            *(ushort4*)&Bs[row * 72 + c4 * 4] = *(ushort4*)u;
        }
        __syncthreads();
#pragma unroll
        for (int kk = 0; kk < 64; kk += 32) {
            bf16x8 af[2], wf[4];
#pragma unroll
            for (int i = 0; i < 2; i++)
                af[i] = *(const bf16x8*)&As[(wm + i * 16 + l15) * 72 + kk + quad * 8];
#pragma unroll
            for (int j = 0; j < 4; j++)
                wf[j] = *(const bf16x8*)&Bs[(j * 16 + l15) * 72 + kk + quad * 8];
#pragma unroll
            for (int i = 0; i < 2; i++)
#pragma unroll
                for (int j = 0; j < 4; j++)
                    acc[i][j] = __builtin_amdgcn_mfma_f32_16x16x32_bf16(af[i], wf[j], acc[i][j], 0, 0, 0);
        }
        __syncthreads();
    }

    // epilogue: bias, bf16 store, column partial stats
    int colbase = c * O_;
    float sj[4], qj[4];
#pragma unroll
    for (int j = 0; j < 4; j++) {
        int col = j * 16 + l15;
        float bb = b0[colbase + col];
        float s = 0.f, q = 0.f;
#pragma unroll
        for (int i = 0; i < 2; i++) {
#pragma unroll
            for (int reg = 0; reg < 4; reg++) {
                float v = acc[i][j][reg] + bb;
                int rl = wm + i * 16 + quad * 4 + reg;
                h0raw[(size_t)(brow0 + rl) * F_ + colbase + col] = f2bf(v);
                s += v; q += v * v;
            }
        }
        s += __shfl_down(s, 32, 64); s += __shfl_down(s, 16, 64);
        q += __shfl_down(q, 32, 64); q += __shfl_down(q, 16, 64);
        sj[j] = s; qj[j] = q;
    }
    __syncthreads();
    float* red = (float*)As;
    if (lane < 16) {
#pragma unroll
        for (int j = 0; j < 4; j++) {
            int col = j * 16 + l15;
            red[col * 4 + w] = sj[j];
            red[256 + col * 4 + w] = qj[j];
        }
    }
    __syncthreads();
    if (tid < 64) {
        float ss = red[tid * 4] + red[tid * 4 + 1] + red[tid * 4 + 2] + red[tid * 4 + 3];
        float qq = red[256 + tid * 4] + red[256 + tid * 4 + 1] + red[256 + tid * 4 + 2] + red[256 + tid * 4 + 3];
        size_t idx = (size_t)bx * F_ + colbase + tid;
        psum[idx] = ss; psq[idx] = qq;
    }
}

// -------------------- fused BN0-stats + BN0-apply + swish + gate MFMA + softmax ------------------
// Each block redundantly finalizes BN0 scale/shift from psum/psq (L2-resident) -> LDS.
// Block 0 additionally zeroes psumE/psqE for the expert GEMM's atomic stats.
__global__ __launch_bounds__(512) void k_bng(const unsigned short* __restrict__ h0,
                                             const float* __restrict__ psum,
                                             const float* __restrict__ psq,
                                             const float* __restrict__ bn0_g,
                                             const float* __restrict__ bn0_b,
                                             const float* __restrict__ gate_w,
                                             const float* __restrict__ gate_b,
                                             unsigned short* __restrict__ h0bf,
                                             float* __restrict__ gates,
                                             float* __restrict__ psumE,
                                             float* __restrict__ psqE) {
    __shared__ __align__(16) unsigned short gwt[16 * 1032];  // [col=t*8+e][f], pad 8
    __shared__ __align__(16) unsigned short As[32 * 1032];   // [row][f] sw bf16, pad 8
    __shared__ float plog[4][32][16];                        // [kq][row][col]
    __shared__ __align__(16) float lsc[1024], lsh[1024];
    int tid = threadIdx.x;
    int brow = blockIdx.x * 32;
    if (blockIdx.x == 0) {
        for (int i = tid; i < 4096; i += 512) { psumE[i] = 0.f; psqE[i] = 0.f; }
    }
    // stage gate_w^T as bf16
    for (int idx = tid; idx < 16 * 1024; idx += 512) {
        int col = idx >> 10, f = idx & 1023;
        int t = col >> 3, e = col & 7;
        gwt[col * 1032 + f] = f2bf(gate_w[(size_t)t * (F_ * E_) + (size_t)f * E_ + e]);
    }
    // BN0 column stats finalize (2 cols/thread)
    {
        int col = tid * 2;
        float s0 = 0.f, s1 = 0.f, q0 = 0.f, q1 = 0.f;
        for (int y = 0; y < 64; y++) {
            float2 pv = *(const float2*)(psum + (size_t)y * F_ + col);
            float2 qv = *(const float2*)(psq + (size_t)y * F_ + col);
            s0 += pv.x; s1 += pv.y; q0 += qv.x; q1 += qv.y;
        }
        float m0 = s0 * (1.0f / B_), m1 = s1 * (1.0f / B_);
        float v0 = q0 * (1.0f / B_) - m0 * m0;
        float v1 = q1 * (1.0f / B_) - m1 * m1;
        float c0 = bn0_g[col] * rsqrtf(v0 + EPS_);
        float c1 = bn0_g[col + 1] * rsqrtf(v1 + EPS_);
        lsc[col] = c0;     lsh[col] = bn0_b[col] - m0 * c0;
        lsc[col + 1] = c1; lsh[col + 1] = bn0_b[col + 1] - m1 * c1;
    }
    __syncthreads();
    // phase 1: BN+swish, write h0bf + LDS
    int f0 = (tid & 255) * 4;
    int rh = tid >> 8;                 // row half: rows rh*16 .. rh*16+15
    float4 sc4 = *(const float4*)&lsc[f0];
    float4 sh4 = *(const float4*)&lsh[f0];
    float scv[4] = { sc4.x, sc4.y, sc4.z, sc4.w };
    float shv[4] = { sh4.x, sh4.y, sh4.z, sh4.w };
#pragma unroll
    for (int r = 0; r < 16; r++) {
        int row = rh * 16 + r;
        ushort4 u = *(const ushort4*)(h0 + (size_t)(brow + row) * F_ + f0);
        unsigned short uu[4] = { u.x, u.y, u.z, u.w };
        unsigned short ov[4];
#pragma unroll
        for (int j = 0; j < 4; j++)
            ov[j] = f2bf(swishf(scv[j] * bf2f(uu[j]) + shv[j]));
        *(ushort4*)(h0bf + (size_t)(brow + row) * F_ + f0) = *(ushort4*)ov;
        *(ushort4*)&As[row * 1032 + f0] = *(ushort4*)ov;
    }
    __syncthreads();
    // phase 2: gate MFMA; wave w -> (row slot, K quarter)
    int w = tid >> 6, lane = tid & 63;
    int l15 = lane & 15, quad = lane >> 4;
    int slot = w & 1, kq = w >> 1;
    f32x4 acc = {};
    const unsigned short* ap = &As[(slot * 16 + l15) * 1032 + kq * 256 + quad * 8];
    const unsigned short* wp = &gwt[l15 * 1032 + kq * 256 + quad * 8];
#pragma unroll
    for (int k0 = 0; k0 < 256; k0 += 32) {
        bf16x8 af = *(const bf16x8*)(ap + k0);
        bf16x8 wf = *(const bf16x8*)(wp + k0);
        acc = __builtin_amdgcn_mfma_f32_16x16x32_bf16(af, wf, acc, 0, 0, 0);
    }
#pragma unroll
    for (int reg = 0; reg < 4; reg++)
        plog[kq][slot * 16 + quad * 4 + reg][l15] = acc[reg];
    __syncthreads();
    // phase 3: per-row softmax over (t,e)
    if (tid < 32) {
        int r = tid;
        float lg[16];
#pragma unroll
        for (int c = 0; c < 16; c++)
            lg[c] = plog[0][r][c] + plog[1][r][c] + plog[2][r][c] + plog[3][r][c] + gate_b[c];
#pragma unroll
        for (int t = 0; t < 2; t++) {
            float mx = -1e30f;
#pragma unroll
            for (int e = 0; e < 8; e++) mx = fmaxf(mx, lg[t * 8 + e]);
            float ex[8], s = 0.f;
#pragma unroll
            for (int e = 0; e < 8; e++) { ex[e] = __expf(lg[t * 8 + e] - mx); s += ex[e]; }
            float inv = 1.0f / s;
#pragma unroll
            for (int e = 0; e < 8; e++)
                gates[(size_t)t * (B_ * E_) + (size_t)(brow + r) * E_ + e] = ex[e] * inv;
        }
    }
}

// -------------------- 256x256 8-phase bf16 MFMA GEMM + atomic stats + last-block finalize --------
__global__ __launch_bounds__(512, 2) void k_gemm256(const unsigned short* __restrict__ A,
                                                    const unsigned short* __restrict__ Wt,
                                                    unsigned short* __restrict__ Cc,
                                                    int N, int K,
                                                    float* __restrict__ psumE,
                                                    float* __restrict__ psqE,
                                                    const float* __restrict__ ebg,
                                                    const float* __restrict__ ebb,
                                                    float* __restrict__ scE,
                                                    float* __restrict__ shE,
                                                    unsigned* __restrict__ ctr) {
    __shared__ __align__(16) unsigned short lds[2][2][2][8192];  // [buf][A0/B1][half][128*64]
    int tid = threadIdx.x;
    int w = tid >> 6, lane = tid & 63;
    int l15 = lane & 15, quad = lane >> 4;
    int wm = w >> 2, wn = w & 3;

    // XCD-aware bijective swizzle (nwg % 8 == 0)
    int lin = blockIdx.y * gridDim.x + blockIdx.x;
    int cpx = (gridDim.x * gridDim.y) >> 3;
    int swz = (lin & 7) * cpx + (lin >> 3);
    int bx = swz & (gridDim.x - 1), by = swz / gridDim.x;
    int row0 = bx * 256, col0 = by * 256;

    int srow = tid >> 3, sperm = (tid & 7) ^ (srow & 7);
    const unsigned short* pA = A  + (size_t)(row0 + srow) * K + sperm * 8;
    const unsigned short* pB = Wt + (size_t)(col0 + srow) * K + sperm * 8;

    int aoffs[2];
#pragma unroll
    for (int kk = 0; kk < 2; kk++)
        aoffs[kk] = l15 * 64 + ((kk * 4 + quad) ^ (l15 & 7)) * 8;

    f32x4 acc[8][4] = {};
    bf16x8 afr[4][2], bfr[2][2];
    int nt = K >> 6;

#define STAGE256(t1, nb) do {                                                              \
    const unsigned short* sA = pA + (size_t)(t1) * 64;                                     \
    const unsigned short* sB = pB + (size_t)(t1) * 64;                                     \
    _Pragma("unroll")                                                                      \
    for (int h = 0; h < 2; h++)                                                            \
        _Pragma("unroll")                                                                  \
        for (int L = 0; L < 2; L++) {                                                      \
            gld16(sA + (size_t)(h * 128 + L * 64) * K, &lds[nb][0][h][w * 512 + L * 4096]);\
            gld16(sB + (size_t)(h * 128 + L * 64) * K, &lds[nb][1][h][w * 512 + L * 4096]);\
        }                                                                                  \
} while (0)

#define LDA256(mh) do {                                                                    \
    _Pragma("unroll")                                                                      \
    for (int mf = 0; mf < 4; mf++)                                                         \
        _Pragma("unroll")                                                                  \
        for (int kk = 0; kk < 2; kk++)                                                     \
            afr[mf][kk] = *(const bf16x8*)(Ab + ((mh) * 4 + mf) * 1024 + aoffs[kk]);       \
} while (0)

#define LDB256(nh) do {                                                                    \
    _Pragma("unroll")                                                                      \
    for (int nf = 0; nf < 2; nf++)                                                         \
        _Pragma("unroll")                                                                  \
        for (int kk = 0; kk < 2; kk++)                                                     \
            bfr[nf][kk] = *(const bf16x8*)(Bb + ((nh) * 2 + nf) * 1024 + aoffs[kk]);       \
} while (0)

#define MMA256(mh, nh) do {                                                                \
    _Pragma("unroll")                                                                      \
    for (int mf = 0; mf < 4; mf++)                                                         \
        _Pragma("unroll")                                                                  \
        for (int nf = 0; nf < 2; nf++)                                                     \
            _Pragma("unroll")                                                              \
            for (int kk = 0; kk < 2; kk++)                                                 \
                acc[(mh) * 4 + mf][(nh) * 2 + nf] = __builtin_amdgcn_mfma_f32_16x16x32_bf16(\
                    afr[mf][kk], bfr[nf][kk], acc[(mh) * 4 + mf][(nh) * 2 + nf], 0, 0, 0); \
} while (0)

#define PHASE_MID()                                                                        \
    __builtin_amdgcn_s_barrier();                                                          \
    asm volatile("s_waitcnt lgkmcnt(0)" ::: "memory");                                     \
    __builtin_amdgcn_sched_barrier(0);                                                     \
    __builtin_amdgcn_s_setprio(1);

#define PHASE_END()                                                                        \
    __builtin_amdgcn_s_setprio(0);                                                         \
    __builtin_amdgcn_sched_barrier(0);                                                     \
    __builtin_amdgcn_s_barrier();

    STAGE256(0, 0);
    asm volatile("s_waitcnt vmcnt(0)" ::: "memory");
    __builtin_amdgcn_s_barrier();

    for (int t = 0; t < nt; t++) {
        int buf = t & 1;
        const unsigned short* Ab = &lds[buf][0][wm][0];
        const unsigned short* Bb = &lds[buf][1][wn >> 1][(wn & 1) * 4096];
        LDA256(0); LDB256(0);
        if (t + 1 < nt) STAGE256(t + 1, buf ^ 1);
        PHASE_MID();
        MMA256(0, 0);
        PHASE_END();
        LDB256(1);
        PHASE_MID();
        MMA256(0, 1);
        PHASE_END();
        LDA256(1);
        PHASE_MID();
        MMA256(1, 1);
        PHASE_END();
        LDB256(0);
        PHASE_MID();
        MMA256(1, 0);
        __builtin_amdgcn_s_setprio(0);
        __builtin_amdgcn_sched_barrier(0);
        asm volatile("s_waitcnt vmcnt(0)" ::: "memory");
        __builtin_amdgcn_s_barrier();
    }
#undef STAGE256
#undef LDA256
#undef LDB256
#undef MMA256
#undef PHASE_MID
#undef PHASE_END

    __syncthreads();

    // epilogue: bf16 C store (C/D layout: col=j*16+l15, row=quad*4+reg)
#pragma unroll
    for (int mf = 0; mf < 8; mf++) {
        int r = row0 + wm * 128 + mf * 16 + quad * 4;
#pragma unroll
        for (int nf = 0; nf < 4; nf++) {
            int cc = col0 + wn * 64 + nf * 16 + l15;
            unsigned short* cp = Cc + (size_t)r * N + cc;
#pragma unroll
            for (int reg = 0; reg < 4; reg++)
                cp[(size_t)reg * N] = f2bf(acc[mf][nf][reg]);
        }
    }

    // fused column partial stats -> atomic accumulate
    float* red = (float*)&lds[0][0][0][0];
    float* redq = red + 512;
    float sj[4], qj[4];
#pragma unroll
    for (int nf = 0; nf < 4; nf++) {
        float s = 0.f, q = 0.f;
#pragma unroll
        for (int mf = 0; mf < 8; mf++)
#pragma unroll
            for (int reg = 0; reg < 4; reg++) {
                float v = acc[mf][nf][reg];
                s += v; q += v * v;
            }
        s += __shfl_down(s, 32, 64); s += __shfl_down(s, 16, 64);
        q += __shfl_down(q, 32, 64); q += __shfl_down(q, 16, 64);
        sj[nf] = s; qj[nf] = q;
    }
    if (quad == 0) {
#pragma unroll
        for (int nf = 0; nf < 4; nf++) {
            int cib = wn * 64 + nf * 16 + l15;
            red[cib * 2 + wm] = sj[nf];
            redq[cib * 2 + wm] = qj[nf];
        }
    }
    __syncthreads();
    if (tid < 256) {
        float s = red[tid * 2] + red[tid * 2 + 1];
        float q = redq[tid * 2] + redq[tid * 2 + 1];
        atomicAdd(&psumE[col0 + tid], s);
        atomicAdd(&psqE[col0 + tid], q);
    }

    // last-block finalize of expert BN scale/shift
    __shared__ int amLast;
    __syncthreads();
    if (tid == 0) {
        __threadfence();
        unsigned old = atomicAdd(ctr, 1u);
        amLast = (old == (unsigned)(gridDim.x * gridDim.y - 1));
    }
    __syncthreads();
    if (amLast) {
        __threadfence();
        for (int n = tid; n < 4096; n += 512) {
            float s = psumE[n], q = psqE[n];
            float mean = s * (1.0f / B_);
            float var = q * (1.0f / B_) - mean * mean;
            float sc = ebg[n] * rsqrtf(var + EPS_);
            scE[n] = sc;
            shE[n] = ebb[n] - mean * sc;
        }
    }
}

// -------------------- expert BN+swish + gate mix -> mix bf16 [t][b][d] --------------------
// block 0 zeroes psumT/psqT for the task GEMM's atomic stats
__global__ __launch_bounds__(256) void k_mix(const unsigned short* __restrict__ eh,
                                             const float* __restrict__ scale,
                                             const float* __restrict__ shift,
                                             const float* __restrict__ gates,
                                             unsigned short* __restrict__ mix,
                                             float* __restrict__ psumT,
                                             float* __restrict__ psqT) {
    __shared__ float scl[E_ * D_], shl[E_ * D_];
    __shared__ float gl[2][2][8];
    int tid = threadIdx.x;
    if (blockIdx.x == 0) {
        for (int i = tid; i < 1024; i += 256) { psumT[i] = 0.f; psqT[i] = 0.f; }
    }
#pragma unroll
    for (int i = 0; i < 4; i++) {
        int li = tid + i * 256;
        ((float4*)scl)[li] = ((const float4*)scale)[li];
        ((float4*)shl)[li] = ((const float4*)shift)[li];
    }
    if (tid < 32) {
        int sub = tid >> 4, t = (tid >> 3) & 1, e = tid & 7;
        gl[sub][t][e] = gates[(size_t)t * (B_ * E_) + (size_t)(blockIdx.x * 2 + sub) * E_ + e];
    }
    __syncthreads();
    int sub = tid >> 7;
    int b = blockIdx.x * 2 + sub;
    int d0 = (tid & 127) * 4;
    float a0[4] = {0.f, 0.f, 0.f, 0.f}, a1[4] = {0.f, 0.f, 0.f, 0.f};
#pragma unroll
    for (int e = 0; e < E_; e++) {
        ushort4 u = *(const ushort4*)&eh[(size_t)b * (E_ * D_) + e * D_ + d0];
        float4 sc4 = *(const float4*)&scl[e * D_ + d0];
        float4 sh4 = *(const float4*)&shl[e * D_ + d0];
        float g0 = gl[sub][0][e], g1 = gl[sub][1][e];
        unsigned short uu[4] = { u.x, u.y, u.z, u.w };
        float scv[4] = { sc4.x, sc4.y, sc4.z, sc4.w };
        float shv[4] = { sh4.x, sh4.y, sh4.z, sh4.w };
#pragma unroll
        for (int l = 0; l < 4; l++) {
            float sw = swishf(scv[l] * bf2f(uu[l]) + shv[l]);
            a0[l] += g0 * sw;
            a1[l] += g1 * sw;
        }
    }
    unsigned short o0[4], o1[4];
#pragma unroll
    for (int l = 0; l < 4; l++) { o0[l] = f2bf(a0[l]); o1[l] = f2bf(a1[l]); }
    *(ushort4*)&mix[(size_t)b * D_ + d0] = *(ushort4*)o0;
    *(ushort4*)&mix[(size_t)(B_ * D_) + (size_t)b * D_ + d0] = *(ushort4*)o1;
}

// -------------------- task GEMM 128x128 + atomic stats + last-block finalize --------------------
__global__ __launch_bounds__(256) void k_gemm_bf16(const unsigned short* __restrict__ A,
                                                   unsigned long long aslab,
                                                   const unsigned short* __restrict__ Wt,
                                                   unsigned long long wslab,
                                                   unsigned short* __restrict__ C,
                                                   unsigned long long cslab, int K,
                                                   float* __restrict__ psumT,
                                                   float* __restrict__ psqT,
                                                   const float* __restrict__ tbg,
                                                   const float* __restrict__ tbb,
                                                   float* __restrict__ scT,
                                                   float* __restrict__ shT,
                                                   unsigned* __restrict__ ctr) {
    __shared__ __align__(16) unsigned short As[128 * 32];
    __shared__ __align__(16) unsigned short Ws[128 * 32];
    int z = blockIdx.z;
    A  += (size_t)z * aslab;
    Wt += (size_t)z * wslab;
    C  += (size_t)z * cslab;
    const int N = gridDim.y * 128;
    int row0 = blockIdx.x * 128, col0 = blockIdx.y * 128;
    int tid = threadIdx.x;
    int w = tid >> 6, lane = tid & 63;
    int l15 = lane & 15, quad = lane >> 4;

    const unsigned short* ga0 = A  + (size_t)(row0 + w * 32 + (lane >> 2)) * K + (lane & 3) * 8;
    const unsigned short* ga1 = ga0 + 16 * (size_t)K;
    const unsigned short* gw0 = Wt + (size_t)(col0 + w * 32 + (lane >> 2)) * K + (lane & 3) * 8;
    const unsigned short* gw1 = gw0 + 16 * (size_t)K;
    unsigned short* la0 = As + (w * 32) * 32;
    unsigned short* la1 = As + (w * 32 + 16) * 32;
    unsigned short* lw0 = Ws + (w * 32) * 32;
    unsigned short* lw1 = Ws + (w * 32 + 16) * 32;

    int wm = (w & 1) * 64, wn = (w >> 1) * 64;
    const unsigned short* Afr = As + (size_t)(wm + l15) * 32 + quad * 8;
    const unsigned short* Wfr = Ws + (size_t)(wn + l15) * 32 + quad * 8;

    f32x4 acc[4][4] = {};

    for (int k0 = 0; k0 < K; k0 += 32) {
        gld16(ga0 + k0, la0);
        gld16(ga1 + k0, la1);
        gld16(gw0 + k0, lw0);
        gld16(gw1 + k0, lw1);
        __syncthreads();
        bf16x8 af[4], wf[4];
#pragma unroll
        for (int i = 0; i < 4; i++) af[i] = *(const bf16x8*)(Afr + i * 16 * 32);
#pragma unroll
        for (int j = 0; j < 4; j++) wf[j] = *(const bf16x8*)(Wfr + j * 16 * 32);
#pragma unroll
        for (int i = 0; i < 4; i++)
#pragma unroll
            for (int j = 0; j < 4; j++)
                acc[i][j] = __builtin_amdgcn_mfma_f32_16x16x32_bf16(af[i], wf[j], acc[i][j], 0, 0, 0);
        __syncthreads();
    }

#pragma unroll
    for (int i = 0; i < 4; i++) {
        int r = row0 + wm + i * 16 + quad * 4;
#pragma unroll
        for (int j = 0; j < 4; j++) {
            int cc = col0 + wn + j * 16 + l15;
            unsigned short* cp = C + (size_t)r * N + cc;
#pragma unroll
            for (int reg = 0; reg < 4; reg++)
                cp[(size_t)reg * N] = f2bf(acc[i][j][reg]);
        }
    }

    float* red = (float*)As;
    float sj[4], qj[4];
#pragma unroll
    for (int j = 0; j < 4; j++) {
        float s = 0.f, q = 0.f;
#pragma unroll
        for (int i = 0; i < 4; i++)
#pragma unroll
            for (int reg = 0; reg < 4; reg++) {
                float v = acc[i][j][reg];
                s += v; q += v * v;
            }
        s += __shfl_down(s, 32, 64); s += __shfl_down(s, 16, 64);
        q += __shfl_down(q, 32, 64); q += __shfl_down(q, 16, 64);
        sj[j] = s; qj[j] = q;
    }
    if (lane < 16) {
#pragma unroll
        for (int j = 0; j < 4; j++) {
            int cib = wn + j * 16 + lane;
            red[cib * 2 + (w & 1)] = sj[j];
            red[256 + cib * 2 + (w & 1)] = qj[j];
        }
    }
    __syncthreads();
    if (tid < 128) {
        float s = red[tid * 2] + red[tid * 2 + 1];
        float q = red[256 + tid * 2] + red[256 + tid * 2 + 1];
        atomicAdd(&psumT[(size_t)z * 512 + col0 + tid], s);
        atomicAdd(&psqT[(size_t)z * 512 + col0 + tid], q);
    }

    // last-block finalize of task BN scale/shift (both tasks)
    __shared__ int amLast;
    __syncthreads();
    if (tid == 0) {
        __threadfence();
        unsigned old = atomicAdd(ctr, 1u);
        amLast = (old == (unsigned)(gridDim.x * gridDim.y * gridDim.z - 1));
    }
    __syncthreads();
    if (amLast) {
        __threadfence();
        for (int idx = tid; idx < 1024; idx += 256) {
            float s = psumT[idx], q = psqT[idx];
            float mean = s * (1.0f / B_);
            float var = q * (1.0f / B_) - mean * mean;
            float sc = tbg[idx] * rsqrtf(var + EPS_);
            scT[idx] = sc;
            shT[idx] = tbb[idx] - mean * sc;
        }
    }
}

// -------------------- task BN+swish + final heads, 8 batch rows per block ------------------------
__global__ __launch_bounds__(256) void k_final(const unsigned short* __restrict__ th,
                                               const float* __restrict__ scale,
                                               const float* __restrict__ shift,
                                               const float* __restrict__ fwa,
                                               const float* __restrict__ fba,
                                               const float* __restrict__ fwb,
                                               const float* __restrict__ fbb,
                                               float* __restrict__ out) {
    __shared__ float t0[8][D_], t1[8][D_];
    __shared__ float pb[64];
    int tid = threadIdx.x;
    int b0 = blockIdx.x * 8;
#pragma unroll
    for (int t = 0; t < 2; t++) {
#pragma unroll
        for (int i = 0; i < 4; i++) {
            int li = tid + i * 256;
            int row = li >> 7, d = (li & 127) * 4;
            ushort4 u = *(const ushort4*)&th[((size_t)t * B_ + b0 + row) * D_ + d];
            unsigned short uu[4] = { u.x, u.y, u.z, u.w };
            float* dst = t ? &t1[row][d] : &t0[row][d];
#pragma unroll
            for (int l = 0; l < 4; l++)
                dst[l] = swishf(scale[t * D_ + d + l] * bf2f(uu[l]) + shift[t * D_ + d + l]);
        }
    }
    __syncthreads();
    {
        int row = tid >> 5, col = tid & 31;
        float acc = fba[col];
        for (int d = 0; d < D_; d++) acc += t0[row][d] * fwa[d * 32 + col];
        out[(size_t)(b0 + row) * OUTW + col] = acc;
    }
    if (tid < 64) {
        int row = tid >> 3, colb = (tid >> 2) & 1, part = tid & 3;
        float a = 0.f;
        for (int d = part * 128; d < part * 128 + 128; d++) a += t1[row][d] * fwb[d * 2 + colb];
        pb[tid] = a;
    }
    __syncthreads();
    if (tid < 16) {
        int row = tid >> 1, colb = tid & 1;
        int base = row * 8 + colb * 4;
        float a = fbb[colb] + pb[base] + pb[base + 1] + pb[base + 2] + pb[base + 3];
        out[(size_t)(b0 + row) * OUTW + 32 + colb] = a;
    }
}

extern "C" void kernel_launch(void* const* d_in, const int* in_sizes, int n_in,
                              void* d_out, int out_size, void* d_ws, size_t ws_size,
                              hipStream_t stream) {
    const float* x        = (const float*)d_in[0];
    const float* w0       = (const float*)d_in[1];
    const float* b0       = (const float*)d_in[2];
    const float* bn0_g    = (const float*)d_in[3];
    const float* bn0_b    = (const float*)d_in[4];
    const float* gate_w   = (const float*)d_in[5];
    const float* gate_b   = (const float*)d_in[6];
    const float* exp_w    = (const float*)d_in[7];
    const float* exp_bn_g = (const float*)d_in[8];
    const float* exp_bn_b = (const float*)d_in[9];
    const float* task_w   = (const float*)d_in[10];
    const float* task_bn_g= (const float*)d_in[11];
    const float* task_bn_b= (const float*)d_in[12];
    const float* fwa      = (const float*)d_in[13];
    const float* fba      = (const float*)d_in[14];
    const float* fwb      = (const float*)d_in[15];
    const float* fbb      = (const float*)d_in[16];
    float* out = (float*)d_out;

    // workspace (float units). Aliases (disjoint lifetimes):
    //   thbf <- ehbf region (ehbf dead after k_mix)
    //   mixbf <- h0raw region (h0raw dead after k_bng)
    float* ws = (float*)d_ws;
    unsigned short* ehbf  = (unsigned short*)ws;              // B*E*D u16 (16,777,216 f)
    unsigned short* h0raw = (unsigned short*)(ws + 16777216); // B*F u16 (4,194,304 f)
    unsigned short* thbf  = ehbf;                             // T*B*D u16 (alias)
    unsigned short* mixbf = h0raw;                            // T*B*D u16 (alias)
    unsigned short* h0bf  = (unsigned short*)(ws + 20971520); // B*F u16 (4,194,304 f)
    unsigned short* wtE   = (unsigned short*)(ws + 25165824); // E*D*F u16 (2,097,152 f)
    unsigned short* twt   = (unsigned short*)(ws + 27262976); // T*D*D u16 (262,144 f)
    float* gates = ws + 27525120;                             // 131,072 f
    float* scE   = ws + 27656192;                             // 4096
    float* shE   = scE + 4096;                                // 4096
    float* scT   = shE + 4096;                                // 1024
    float* shT   = scT + 1024;                                // 1024
    float* psum  = shT + 1024;                                // 65,536 f (64 x 1024)
    float* psq   = psum + 65536;                              // 65,536 f
    float* psumE = psq + 65536;                               // 4096
    float* psqE  = psumE + 4096;                              // 4096
    float* psumT = psqE + 4096;                               // 1024
    float* psqT  = psumT + 1024;                              // 1024
    unsigned* ctrs = (unsigned*)(psqT + 1024);                // 2 counters

    // 1) merged: weight transposes + split linear + counter zero   (1024 split + 4608 wt blocks)
    k_pre<<<dim3(5632), 256, 0, stream>>>(x, w0, b0, h0raw, psum, psq,
                                          exp_w, wtE, task_w, twt, ctrs);
    // 2) fused BN0 stats + apply + swish + gate MFMA + softmax (also zeroes psumE/psqE)
    k_bng<<<dim3(256), 512, 0, stream>>>(h0raw, psum, psq, bn0_g, bn0_b,
                                         gate_w, gate_b, h0bf, gates, psumE, psqE);
    // 3) expert GEMM + atomic stats + last-block scE/shE finalize
    k_gemm256<<<dim3(32, 16), 512, 0, stream>>>(h0bf, wtE, ehbf, E_ * D_, F_,
                                                psumE, psqE, exp_bn_g, exp_bn_b,
                                                scE, shE, &ctrs[0]);
    // 4) expert BN apply + swish + gate mix (also zeroes psumT/psqT)
    k_mix<<<dim3(B_ / 2), 256, 0, stream>>>(ehbf, scE, shE, gates, mixbf, psumT, psqT);
    // 5) task GEMM + atomic stats + last-block scT/shT finalize
    k_gemm_bf16<<<dim3(64, 4, 2), 256, 0, stream>>>(mixbf, (unsigned long long)(B_ * D_),
                                                    twt, (unsigned long long)(D_ * D_),
                                                    thbf, (unsigned long long)(B_ * D_), D_,
                                                    psumT, psqT, task_bn_g, task_bn_b,
                                                    scT, shT, &ctrs[1]);
    // 6) task BN apply + swish + final heads -> out [B, 34]
    k_final<<<dim3(B_ / 8), 256, 0, stream>>>(thbf, scT, shT, fwa, fba, fwb, fbb, out);
}